// Round 13
// baseline (802.444 us; speedup 1.0000x reference)
//
#include <hip/hip_runtime.h>
#include <hip/hip_bf16.h>

typedef unsigned short u16;
typedef unsigned int   u32;

static const int Nn  = 100000;
static const int Ne  = 800000;
static const int Ll  = 3;
static const int SCAN_B = 98;  // ceil(100000/1024)

typedef short     short8  __attribute__((ext_vector_type(8)));
typedef float     floatx4 __attribute__((ext_vector_type(4)));

// ---- cumulative f32-weight offsets (inputs 4..21 concatenated into W) ----
static const int H_CUM[19] = {
  0, 86016, 86208, 98496, 98688, 101760, 101808, 103152, 103248,
  129360, 130176, 133248, 133440, 134208, 134400, 134592, 135360, 135552, 135744
};
static const int H_SZ[18] = {
  86016, 192, 12288, 192, 3072, 48, 1344, 96,
  26112, 816, 3072, 192, 768, 192, 192, 768, 192, 192
};

union FU { u32 u; float f; };
__device__ __forceinline__ float b2f(u16 v) { FU x; x.u = ((u32)v) << 16; return x.f; }
__device__ __forceinline__ float lo2f(u32 w) { FU x; x.u = w << 16; return x.f; }
__device__ __forceinline__ float hi2f(u32 w) { FU x; x.u = w & 0xffff0000u; return x.f; }
__device__ __forceinline__ u16 f2b(float f) {
  FU x; x.f = f;
  u32 u = x.u;
  u32 r = (u + 0x7FFFu + ((u >> 16) & 1u)) >> 16;
  return (u16)r;
}
__device__ __forceinline__ u32 pk2(float a, float b) {
  __hip_bfloat162 h2 = __float22bfloat162_rn(make_float2(a, b));
  union { __hip_bfloat162 h; u32 u; } c; c.h = h2; return c.u;
}

// ---- fold BN (eval) into A*x+B per layer; layout per layer (320 f32) ----
__global__ void k_bnprep(const float* __restrict__ W, float* __restrict__ bnAB) {
  int idx = blockIdx.x * blockDim.x + threadIdx.x;
  if (idx >= 480) return;
  int i = idx / 160, d0 = idx % 160;
  const float* src; float* dstA; float* dstB; int dim, d;
  if (d0 < 64)       { d = d0;      src = W + 133440 + i * 256; dim = 64; dstA = bnAB + i*320 + 0;   dstB = bnAB + i*320 + 64;  }
  else if (d0 < 80)  { d = d0 - 64; src = W + 134208 + i * 64;  dim = 16; dstA = bnAB + i*320 + 128; dstB = bnAB + i*320 + 144; }
  else if (d0 < 96)  { d = d0 - 80; src = W + 134400 + i * 64;  dim = 16; dstA = bnAB + i*320 + 160; dstB = bnAB + i*320 + 176; }
  else               { d = d0 - 96; src = W + 134592 + i * 256; dim = 64; dstA = bnAB + i*320 + 192; dstB = bnAB + i*320 + 256; }
  float g = src[0*dim+d], b = src[1*dim+d], m = src[2*dim+d], v = src[3*dim+d];
  float A = g * rsqrtf(v + 1e-5f);
  float B = b - m * A;
  dstA[d] = A; dstB[d] = B;
}

// ---- Bsw prep: B-fragment-ordered bf16 Wk2 (for k_msg), K order flat = jp*32+q ----
__global__ void k_prep(const float* __restrict__ W, u16* __restrict__ BswG) {
  int i = blockIdx.x * 256 + threadIdx.x;
  if (i >= 3 * 8704) return;
  int layer = i / 8704, r = i % 8704;
  int jp = r / 512, l2 = r % 512;
  int lane = l2 / 8, j = l2 % 8;
  int q = (lane >> 4) * 8 + j, n = lane & 15;
  const float* Wk2 = W + 103248 + layer * 8704;
  BswG[i] = f2b(Wk2[q * 272 + jp * 16 + n]);
}

// ---- Bsw2 prep: B-fragment-ordered hi/lo bf16 [Wrel | Wself] for k_rel2 ----
__global__ void k_prep2(const float* __restrict__ W, u16* __restrict__ B2) {
  int idx = blockIdx.x * 256 + threadIdx.x;
  if (idx >= 3 * 65536) return;
  int layer = idx >> 16, r = idx & 65535;
  int fr = r >> 9;                 // 0..127 = nc*16 + nt*4 + ks*2 + hl
  int lane = (r >> 3) & 63, j = r & 7;
  int hl = fr & 1, ks = (fr >> 1) & 1, nt = (fr >> 2) & 3, nc = fr >> 4;
  int k = ks * 32 + (lane >> 4) * 8 + j;          // K index 0..63
  int g = nc * 64 + nt * 16 + (lane & 15);        // output col 0..511
  const float* Wrel  = W + layer * 28672;                  // H_CUM[0]
  const float* Wself = W + 86208 + layer * 4096;           // H_CUM[2]
  float v = (g < 448) ? Wrel[((g >> 6) * 64 + k) * 64 + (g & 63)]
                      : Wself[k * 64 + (g - 448)];
  u16 hi = f2b(v);
  B2[idx] = hl ? f2b(v - b2f(hi)) : hi;
}

// ---- Wk1 fragment prep for MFMA a-compute in k_msg ----
__global__ void k_prep3(const float* __restrict__ W, u16* __restrict__ Wk1f) {
  int idx = blockIdx.x * 256 + threadIdx.x;
  if (idx >= 3 * 2048) return;
  int layer = idx / 2048, r = idx % 2048;
  int kind = (r >> 10) & 1, nt = (r >> 9) & 1;
  int lane = (r >> 3) & 63, j = r & 7;
  int k = (lane >> 4) * 8 + j;
  int q = nt * 16 + (lane & 15);
  const float* Wk1 = W + 101808 + layer * 448;
  u16 out = 0;
  if (kind == 0) {
    if (k < 14)       out = f2b(Wk1[k * 32 + q]);
    else if (k < 28)  out = f2b(Wk1[(k - 14) * 32 + q]);
  } else {
    if (k < 14) {
      float w = Wk1[k * 32 + q];
      u16 hi = f2b(w);
      out = f2b(w - b2f(hi));
    }
  }
  Wk1f[idx] = out;
}

// ---- u[i] = normalize(pos[i]-pos[i-1]) ----
__global__ void k_u(const float* __restrict__ posf, float* __restrict__ u) {
  int i = blockIdx.x * blockDim.x + threadIdx.x;
  if (i >= Nn) return;
  float ux, uy, uz;
  if (i == 0) { ux = uy = uz = 0.57735026918962584f; }
  else {
    float vx = posf[i*3+0] - posf[(i-1)*3+0];
    float vy = posf[i*3+1] - posf[(i-1)*3+1];
    float vz = posf[i*3+2] - posf[(i-1)*3+2];
    float nrm = sqrtf(vx*vx + vy*vy + vz*vz);
    float inv = 1.0f / fmaxf(nrm, 1e-12f);
    ux = vx*inv; uy = vy*inv; uz = vz*inv;
  }
  u[i*3+0] = ux; u[i*3+1] = uy; u[i*3+2] = uz;
}

// ---- frame[i] = [b, n, cross(b,n)] stored [j*3+k] ----
__global__ void k_frame(const float* __restrict__ u, float* __restrict__ frame) {
  int i = blockIdx.x * blockDim.x + threadIdx.x;
  if (i >= Nn) return;
  float bx, by, bz, nx, ny, nz;
  if (i < Nn - 1) {
    float ax = u[i*3+0], ay = u[i*3+1], az = u[i*3+2];
    float cx = u[(i+1)*3+0], cy = u[(i+1)*3+1], cz = u[(i+1)*3+2];
    float dx = ax-cx, dy = ay-cy, dz = az-cz;
    float n1 = sqrtf(dx*dx + dy*dy + dz*dz);
    float i1 = 1.0f / fmaxf(n1, 1e-12f);
    bx = dx*i1; by = dy*i1; bz = dz*i1;
    float qx = ay*cz - az*cy, qy = az*cx - ax*cz, qz = ax*cy - ay*cx;
    float n2 = sqrtf(qx*qx + qy*qy + qz*qz);
    float i2 = 1.0f / fmaxf(n2, 1e-12f);
    nx = qx*i2; ny = qy*i2; nz = qz*i2;
  } else {
    bx = by = bz = 0.57735026918962584f;
    nx = ny = nz = 0.57735026918962584f;
  }
  float ex = by*nz - bz*ny, ey = bz*nx - bx*nz, ez = bx*ny - by*nx;
  frame[i*9+0] = bx; frame[i*9+1] = nx; frame[i*9+2] = ex;
  frame[i*9+3] = by; frame[i*9+4] = ny; frame[i*9+5] = ey;
  frame[i*9+6] = bz; frame[i*9+7] = nz; frame[i*9+8] = ez;
}

// ---- per-edge geometry (layer-invariant): t,r -> f32 SoA; + degree count ----
__global__ void k_edge(const int* __restrict__ EI, const float* __restrict__ posf,
                       const float* __restrict__ frame,
                       float* __restrict__ t0, float* __restrict__ t1, float* __restrict__ t2,
                       float* __restrict__ r0, float* __restrict__ r1, float* __restrict__ r2,
                       int* __restrict__ cnt) {
  int e = blockIdx.x * 256 + threadIdx.x;
  int vin = EI[e], vout = EI[Ne + e];
  float fi[9], fo[9];
#pragma unroll
  for (int t = 0; t < 9; t++) fi[t] = frame[(size_t)vin*9 + t];
#pragma unroll
  for (int t = 0; t < 9; t++) fo[t] = frame[(size_t)vout*9 + t];
  float d0 = posf[vout*3+0] - posf[vin*3+0];
  float d1 = posf[vout*3+1] - posf[vin*3+1];
  float d2 = posf[vout*3+2] - posf[vin*3+2];
  float tt[3], rr[3];
#pragma unroll
  for (int k = 0; k < 3; k++) {
    tt[k] = fi[0*3+k]*d0 + fi[1*3+k]*d1 + fi[2*3+k]*d2;
    rr[k] = fi[0*3+k]*fo[0*3+k] + fi[1*3+k]*fo[1*3+k] + fi[2*3+k]*fo[2*3+k];
  }
  t0[e] = tt[0]; t1[e] = tt[1]; t2[e] = tt[2];
  r0[e] = rr[0]; r1[e] = rr[1]; r2[e] = rr[2];
  atomicAdd(&cnt[vout], 1);
}

// ---- multi-block scan ----
__global__ __launch_bounds__(1024) void k_scan1(const int* __restrict__ cnt,
                                                int* __restrict__ locExc,
                                                int* __restrict__ btot) {
  __shared__ int sm[1024];
  int t = threadIdx.x, b = blockIdx.x;
  int i = b * 1024 + t;
  int v = (i < Nn) ? cnt[i] : 0;
  sm[t] = v;
  __syncthreads();
#pragma unroll
  for (int off = 1; off < 1024; off <<= 1) {
    int x = (t >= off) ? sm[t - off] : 0;
    __syncthreads();
    sm[t] += x;
    __syncthreads();
  }
  if (i < Nn) locExc[i] = sm[t] - v;
  if (t == 1023) btot[b] = sm[1023];
}

__global__ void k_scan2(const int* __restrict__ btot, int* __restrict__ boff,
                        int* __restrict__ rowptr) {
  if (threadIdx.x != 0 || blockIdx.x != 0) return;
  int run = 0;
  for (int b = 0; b < SCAN_B; b++) { boff[b] = run; run += btot[b]; }
  rowptr[Nn] = run;
}

__global__ void k_scan3(const int* __restrict__ cnt, const int* __restrict__ locExc,
                        const int* __restrict__ boff, int* __restrict__ rowptr,
                        float* __restrict__ deginv) {
  int i = blockIdx.x * blockDim.x + threadIdx.x;
  if (i >= Nn) return;
  rowptr[i] = locExc[i] + boff[i >> 10];
  int dv = cnt[i] > 1 ? cnt[i] : 1;
  deginv[i] = 1.0f / (float)dv;
}

// ---- place: CSR-ordered Y-offsets ----
__global__ void k_place(const int* __restrict__ EI, const int* __restrict__ EREL,
                        const int* __restrict__ rowptr,
                        int* __restrict__ fill, int* __restrict__ yidx) {
  int e = blockIdx.x * blockDim.x + threadIdx.x;
  if (e >= Ne) return;
  int vout = EI[Ne + e];
  int p = atomicAdd(&fill[vout], 1);
  int slot = rowptr[vout] + p;
  yidx[slot] = EI[e] * 448 + EREL[e] * 64;
}

// ---- MFMA rel: C[n, 0..511] = h[n,0..63] @ [Wrel(7) | Wself], hi/lo bf16 split ----
__global__ __launch_bounds__(256) void k_rel2(
    const float* __restrict__ h, const u16* __restrict__ Bsw,
    const float* __restrict__ brel, const float* __restrict__ bself,
    u16* __restrict__ Y, u16* __restrict__ S) {
  __shared__ uint4 bs4[1024];   // 16 KB: 16 frags x 64 uint4
  int tid = threadIdx.x;
  int w = tid >> 6, lane = tid & 63;
  int kq = lane >> 4, cl = lane & 15;
  int nb0 = blockIdx.x * 64;
  int anode = nb0 + w * 16 + cl;       // A-row node for this lane
  union U { uint4 u; short8 v; };

  // build A fragments (hi/lo) once: A[row=cl][k = ks*32 + kq*8 + j]
  uint4 Ah[2], Al[2];
#pragma unroll
  for (int ks = 0; ks < 2; ks++) {
    float p[8] = {0.f,0.f,0.f,0.f,0.f,0.f,0.f,0.f};
    if (anode < Nn) {
      const float4* hp = (const float4*)(h + (size_t)anode * 64 + ks * 32 + kq * 8);
      float4 q0 = hp[0], q1 = hp[1];
      p[0]=q0.x; p[1]=q0.y; p[2]=q0.z; p[3]=q0.w;
      p[4]=q1.x; p[5]=q1.y; p[6]=q1.z; p[7]=q1.w;
    }
    u32 hw[4], lw[4];
#pragma unroll
    for (int t = 0; t < 4; t++) {
      u16 ha = f2b(p[2*t]), hb = f2b(p[2*t+1]);
      hw[t] = (u32)ha | ((u32)hb << 16);
      lw[t] = pk2(p[2*t] - b2f(ha), p[2*t+1] - b2f(hb));
    }
    Ah[ks] = make_uint4(hw[0], hw[1], hw[2], hw[3]);
    Al[ks] = make_uint4(lw[0], lw[1], lw[2], lw[3]);
  }

  for (int nc = 0; nc < 8; nc++) {
    if (nc) __syncthreads();
    const uint4* src = (const uint4*)(Bsw + nc * 8192);
#pragma unroll
    for (int i = 0; i < 4; i++) bs4[tid + i * 256] = src[tid + i * 256];
    __syncthreads();

    floatx4 acc[4];
#pragma unroll
    for (int nt = 0; nt < 4; nt++) acc[nt] = (floatx4){0.f, 0.f, 0.f, 0.f};
#pragma unroll
    for (int nt = 0; nt < 4; nt++) {
#pragma unroll
      for (int ks = 0; ks < 2; ks++) {
        U bh, bl, ah, al;
        bh.u = bs4[((nt*2 + ks)*2 + 0)*64 + lane];
        bl.u = bs4[((nt*2 + ks)*2 + 1)*64 + lane];
        ah.u = Ah[ks]; al.u = Al[ks];
        acc[nt] = __builtin_amdgcn_mfma_f32_16x16x32_bf16(ah.v, bh.v, acc[nt], 0, 0, 0);
        acc[nt] = __builtin_amdgcn_mfma_f32_16x16x32_bf16(al.v, bh.v, acc[nt], 0, 0, 0);
        acc[nt] = __builtin_amdgcn_mfma_f32_16x16x32_bf16(ah.v, bl.v, acc[nt], 0, 0, 0);
      }
    }
    // D layout: col = lane&15, row = (lane>>4)*4 + reg
    if (nc < 7) {
#pragma unroll
      for (int nt = 0; nt < 4; nt++) {
#pragma unroll
        for (int reg = 0; reg < 4; reg++) {
          int node = nb0 + w * 16 + kq * 4 + reg;
          if (node < Nn)
            Y[(size_t)node * 448 + nc * 64 + nt * 16 + cl] = f2b(acc[nt][reg]);
        }
      }
    } else {
#pragma unroll
      for (int nt = 0; nt < 4; nt++) {
        int c = nt * 16 + cl;
        float bias = brel[c] + bself[c];
#pragma unroll
        for (int reg = 0; reg < 4; reg++) {
          int node = nb0 + w * 16 + kq * 4 + reg;
          if (node < Nn)
            S[(size_t)node * 64 + c] = f2b(acc[nt][reg] + bias);
        }
      }
    }
  }
}

// ---- per-node z + bias precompute ----
__global__ __launch_bounds__(256) void k_z(
    const float* __restrict__ h, const float* __restrict__ Wl1, const float* __restrict__ bl1,
    const float* __restrict__ bk2, const float* __restrict__ bn,
    u16* __restrict__ zt, u16* __restrict__ biast) {
  __shared__ float ls[64][65];
  __shared__ float zz[64][17];
  int tid = threadIdx.x;
  int nb0 = blockIdx.x * 64;
  const float* Ain = bn + 0;
  const float* Bin = bn + 64;
#pragma unroll
  for (int r = 0; r < 16; r++) {
    int idx = r * 256 + tid;
    int row = idx >> 6, col = idx & 63;
    int node = nb0 + row;
    float v = (node < Nn) ? h[(size_t)node * 64 + col] : 0.0f;
    ls[row][col] = fmaxf(v * Ain[col] + Bin[col], 0.0f);
  }
  __syncthreads();
  int row = tid >> 2, jq = (tid & 3) * 4;
  int node = nb0 + row;
  const float* Amsg = bn + 128;
  const float* Bmsg = bn + 144;
  float m1[4];
#pragma unroll
  for (int t = 0; t < 4; t++) m1[t] = bl1[jq + t];
  for (int c = 0; c < 64; c++) {
    float lv = ls[row][c];
#pragma unroll
    for (int t = 0; t < 4; t++) m1[t] += lv * Wl1[c * 16 + jq + t];
  }
  float zv[4];
#pragma unroll
  for (int t = 0; t < 4; t++) {
    zv[t] = fmaxf(m1[t] * Amsg[jq + t] + Bmsg[jq + t], 0.0f);
    zz[row][jq + t] = zv[t];
  }
  if (node < Nn) {
    u32* zg = (u32*)zt + (size_t)node * 8 + (tid & 3) * 2;
    zg[0] = pk2(zv[0], zv[1]);
    zg[1] = pk2(zv[2], zv[3]);
  }
  __syncthreads();
  float bb[4];
#pragma unroll
  for (int t = 0; t < 4; t++) bb[t] = bk2[jq + t];
  for (int j = 0; j < 16; j++) {
    float zj = zz[row][j];
#pragma unroll
    for (int t = 0; t < 4; t++) bb[t] += zj * bk2[(j + 1) * 16 + jq + t];
  }
  if (node < Nn) {
    u32* bg = (u32*)biast + (size_t)node * 8 + (tid & 3) * 2;
    bg[0] = pk2(bb[0], bb[1]);
    bg[1] = pk2(bb[2], bb[3]);
  }
}

// ---- per-edge MFMA kernel: B frags from L2; atomic segment-sum into moacc ----
__global__ __launch_bounds__(256) void k_msg(
    const float* __restrict__ t0, const float* __restrict__ t1, const float* __restrict__ t2,
    const float* __restrict__ r0, const float* __restrict__ r1, const float* __restrict__ r2,
    const int* __restrict__ EI,
    const u16* __restrict__ zt, const u16* __restrict__ biast,
    const u16* __restrict__ Wk1f, const float* __restrict__ bk1,
    const u16* __restrict__ BswG, float* __restrict__ moacc) {
  __shared__ u16 abuf[256 * 40];   // ef->a rows, stride 40 u16 (80 B) -> 20480 B
  __shared__ int ivin[256];        // 1024 B
  __shared__ int ivout[256];       // 1024 B   (total 22528 B -> 7 blocks/CU)

  int tid = threadIdx.x;
  int e0 = blockIdx.x * 256;
  int e = e0 + tid;

  int vin = EI[e], vout = EI[Ne + e];
  ivin[tid] = vin;
  ivout[tid] = vout;

  float ef[14];
  ef[0] = t0[e]; ef[1] = t1[e]; ef[2] = t2[e];
  ef[3] = r0[e]; ef[4] = r1[e]; ef[5] = r2[e];
  int ad = vin - vout; if (ad < 0) ad = -ad;
  ef[6] = ((float)ad) / 6.0f;
#pragma unroll
  for (int k = 0; k < 7; k++) ef[7+k] = 1.0f - 2.0f*fabsf(ef[k]);

  // pack ef hi/lo A-row: k=0..13 hi, 14..27 lo, 28..31 zero
  u16 row[32];
#pragma unroll
  for (int d = 0; d < 14; d++) {
    u16 hi = f2b(ef[d]);
    row[d] = hi;
    row[14 + d] = f2b(ef[d] - b2f(hi));
  }
#pragma unroll
  for (int d = 28; d < 32; d++) row[d] = 0;
  u32* ar = (u32*)(abuf + (size_t)tid * 40);
#pragma unroll
  for (int i = 0; i < 16; i++)
    ar[i] = (u32)row[2*i] | ((u32)row[2*i+1] << 16);
  __syncthreads();

  int lane = tid & 63, w4 = (tid >> 6) * 4;
  int m = lane & 15, quad = lane >> 4;
  union U { uint4 u; short8 v; };

  // a-GEMM B fragments (global, tiny L2-hot table) + bk1 per output col
  U b0[2], b1[2];
#pragma unroll
  for (int nt = 0; nt < 2; nt++) {
    b0[nt].u = *(const uint4*)(Wk1f + 0*1024 + nt*512 + lane*8);
    b1[nt].u = *(const uint4*)(Wk1f + 1*1024 + nt*512 + lane*8);
  }
  float bk1v[2] = { bk1[m], bk1[16 + m] };
  const u16* bswL = BswG + (size_t)lane * 8;   // per-lane base into B-frag table

#pragma unroll
  for (int t = 0; t < 4; t++) {
    int s0 = (w4 + t) * 16;
    const u16* rs0 = abuf + (size_t)(s0 + m) * 40;

    // ---- a = relu(ef @ Wk1 + bk1) via 2x2 MFMAs, written back in place ----
    U efr; efr.u = *(const uint4*)(rs0 + quad * 8);
#pragma unroll
    for (int nt = 0; nt < 2; nt++) {
      floatx4 aa = {0.f, 0.f, 0.f, 0.f};
      aa = __builtin_amdgcn_mfma_f32_16x16x32_bf16(efr.v, b0[nt].v, aa, 0, 0, 0);
      aa = __builtin_amdgcn_mfma_f32_16x16x32_bf16(efr.v, b1[nt].v, aa, 0, 0, 0);
#pragma unroll
      for (int reg = 0; reg < 4; reg++) {
        int se = s0 + quad * 4 + reg;
        float av = fmaxf(aa[reg] + bk1v[nt], 0.0f);
        abuf[(size_t)se * 40 + nt * 16 + m] = f2b(av);
      }
    }
    U afr; afr.u = *(const uint4*)(rs0 + quad * 8);   // re-read: now 'a'

    // ---- row metadata: z (2x uint4), bias, vout for the 4 owned rows ----
    int se0 = s0 + quad * 4;
    uint4 z0[4], z1[4]; float bv[4]; int vo[4];
#pragma unroll
    for (int reg = 0; reg < 4; reg++) {
      int vi = ivin[se0 + reg];
      const uint4* zp = (const uint4*)(zt + (size_t)vi * 16);
      z0[reg] = zp[0]; z1[reg] = zp[1];
      bv[reg] = b2f(biast[(size_t)vi * 16 + m]);
      vo[reg] = ivout[se0 + reg];
    }

    // ---- ker MFMAs (B frags from L2) with immediate per-jp consume ----
    float acc[4];
    {
      U bfr; bfr.u = *(const uint4*)(bswL);
      floatx4 zz4 = {0.f, 0.f, 0.f, 0.f};
      floatx4 k0 = __builtin_amdgcn_mfma_f32_16x16x32_bf16(afr.v, bfr.v, zz4, 0, 0, 0);
#pragma unroll
      for (int reg = 0; reg < 4; reg++) acc[reg] = k0[reg];
    }
#pragma unroll
    for (int jp = 1; jp <= 16; jp++) {
      U bfr; bfr.u = *(const uint4*)(bswL + (size_t)jp * 512);
      floatx4 zz4 = {0.f, 0.f, 0.f, 0.f};
      floatx4 kj = __builtin_amdgcn_mfma_f32_16x16x32_bf16(afr.v, bfr.v, zz4, 0, 0, 0);
      const int zi = jp - 1;
#pragma unroll
      for (int reg = 0; reg < 4; reg++) {
        const u32* zw = (zi < 8) ? (const u32*)&z0[reg] : (const u32*)&z1[reg];
        u32 wv = zw[(zi & 7) >> 1];
        float zv = (zi & 1) ? hi2f(wv) : lo2f(wv);
        acc[reg] += zv * kj[reg];
      }
    }
#pragma unroll
    for (int reg = 0; reg < 4; reg++)
      atomicAdd(&moacc[(size_t)vo[reg] * 16 + m], acc[reg] + bv[reg]);
  }
}

// ---- per-node: 2x-unrolled Y gather + moacc read, residual, LN ----
__global__ __launch_bounds__(256) void k_node(
    const float* __restrict__ h, const u16* __restrict__ S, const u16* __restrict__ Y,
    const int* __restrict__ rowptr, const int* __restrict__ yidx,
    const float* __restrict__ moacc, const float* __restrict__ deginv,
    const float* __restrict__ Wl2, const float* __restrict__ bl2,
    const float* __restrict__ bn, const float* __restrict__ lng, const float* __restrict__ lnb,
    float* __restrict__ hout) {
  __shared__ float relsm[4][64];
  __shared__ float u2s[4][16];
  int tid = threadIdx.x;
  int lane = tid & 63, w = tid >> 6;
  int n = blockIdx.x * 4 + w;
  bool act = (n < Nn);

  if (act) {
    int beg = rowptr[n], end = rowptr[n+1];

    // ---- part A: rel sum over Y rows; 2 rounds unrolled -> 2 loads in flight ----
    int g = lane >> 4, col4 = lane & 15;
    float a4[4] = {0.f, 0.f, 0.f, 0.f};
    for (int c0 = beg; c0 < end; c0 += 64) {
      int l = c0 + lane;
      int yo = (l < end) ? yidx[l] : 0;
      int cnt = end - c0; if (cnt > 64) cnt = 64;
      for (int j0 = 0; j0 < cnt; j0 += 8) {
        int jA = j0 + g;
        int jB = j0 + 4 + g;
        int yA = __shfl(yo, jA, 64);
        int yB = __shfl(yo, jB, 64);
        bool vA = (jA < cnt), vB = (jB < cnt);
        uint2 dA = vA ? *(const uint2*)(Y + (size_t)yA + col4 * 4) : make_uint2(0u, 0u);
        uint2 dB = vB ? *(const uint2*)(Y + (size_t)yB + col4 * 4) : make_uint2(0u, 0u);
        a4[0] += lo2f(dA.x); a4[1] += hi2f(dA.x);
        a4[2] += lo2f(dA.y); a4[3] += hi2f(dA.y);
        a4[0] += lo2f(dB.x); a4[1] += hi2f(dB.x);
        a4[2] += lo2f(dB.y); a4[3] += hi2f(dB.y);
      }
    }
#pragma unroll
    for (int t = 0; t < 4; t++) {
      a4[t] += __shfl_xor(a4[t], 16, 64);
      a4[t] += __shfl_xor(a4[t], 32, 64);
    }
    if (lane < 16) {
#pragma unroll
      for (int t = 0; t < 4; t++) relsm[w][col4 * 4 + t] = a4[t];
    }

    // ---- part B: read atomically-accumulated moacc (f32), BN + relu ----
    const float* Aupd = bn + 160;
    const float* Bupd = bn + 176;
    if (lane < 16) {
      float v = moacc[(size_t)n * 16 + lane] * deginv[n];
      u2s[w][lane] = fmaxf(v * Aupd[lane] + Bupd[lane], 0.0f);
    }
  }
  __syncthreads();
  if (act) {
    float rel_out = fmaxf(b2f(S[(size_t)n*64 + lane]) + relsm[w][lane], 0.0f);
    float ie = bl2[lane];
#pragma unroll
    for (int j = 0; j < 16; j++) ie += u2s[w][j] * Wl2[j*64 + lane];
    const float* Aout = bn + 192;
    const float* Bout = bn + 256;
    ie = ie * Aout[lane] + Bout[lane];
    float hidden = rel_out + ie + h[(size_t)n*64 + lane];
    float s = hidden;
#pragma unroll
    for (int off = 32; off > 0; off >>= 1) s += __shfl_xor(s, off, 64);
    float mu = s * (1.0f/64.0f);
    float d = hidden - mu;
    float s2 = d * d;
#pragma unroll
    for (int off = 32; off > 0; off >>= 1) s2 += __shfl_xor(s2, off, 64);
    float var = s2 * (1.0f/64.0f);
    float o = d * rsqrtf(var + 1e-5f) * lng[lane] + lnb[lane];
    hout[(size_t)n*64 + lane] = o;
  }
}

extern "C" void kernel_launch(void* const* d_in, const int* in_sizes, int n_in,
                              void* d_out, int out_size, void* d_ws, size_t ws_size,
                              hipStream_t stream) {
  const float* x    = (const float*)d_in[0];
  const float* posf = (const float*)d_in[1];
  const int* EI     = (const int*)d_in[2];
  const int* EREL   = (const int*)d_in[3];
  float* outf       = (float*)d_out;

  char* p = (char*)d_ws;
  auto alloc = [&](size_t bytes) -> char* {
    char* r = p;
    p += (bytes + 255) & ~((size_t)255);
    return r;
  };
  float* W      = (float*)alloc((size_t)135744 * 4);
  float* bnAB   = (float*)alloc((size_t)960 * 4);
  u16*   BswG   = (u16*)  alloc((size_t)3 * 8704 * 2);
  u16*   Bsw2   = (u16*)  alloc((size_t)3 * 65536 * 2);
  u16*   Wk1f   = (u16*)  alloc((size_t)3 * 2048 * 2);
  float* u      = (float*)alloc((size_t)Nn * 3 * 4);
  float* frame  = (float*)alloc((size_t)Nn * 9 * 4);
  int*   cnt    = (int*)  alloc((size_t)Nn * 4);
  int*   fill   = (int*)  alloc((size_t)Nn * 4);
  int*   rowptr = (int*)  alloc((size_t)(Nn + 1) * 4);
  int*   locExc = (int*)  alloc((size_t)Nn * 4);
  int*   btot   = (int*)  alloc((size_t)SCAN_B * 4);
  int*   boff   = (int*)  alloc((size_t)SCAN_B * 4);
  int*   yidx   = (int*)  alloc((size_t)Ne * 4);
  float* deginv = (float*)alloc((size_t)Nn * 4);
  float* h      = (float*)alloc((size_t)Nn * 64 * 4);
  u16*   S      = (u16*)  alloc((size_t)Nn * 64 * 2);
  u16*   Y      = (u16*)  alloc((size_t)Nn * 448 * 2);
  float* moacc  = (float*)alloc((size_t)Nn * 16 * 4);
  u16*   zt     = (u16*)  alloc((size_t)Nn * 16 * 2);
  u16*   biast  = (u16*)  alloc((size_t)Nn * 16 * 2);
  float* et0    = (float*)alloc((size_t)Ne * 4);
  float* et1    = (float*)alloc((size_t)Ne * 4);
  float* et2    = (float*)alloc((size_t)Ne * 4);
  float* er0    = (float*)alloc((size_t)Ne * 4);
  float* er1    = (float*)alloc((size_t)Ne * 4);
  float* er2    = (float*)alloc((size_t)Ne * 4);
  (void)n_in; (void)in_sizes; (void)out_size;

  size_t needed = (size_t)(p - (char*)d_ws);
  if (needed > ws_size) return;  // diagnostic: zero output => absmax == max|ref| (~4.75)

  hipMemsetAsync(cnt,  0, (size_t)Nn * 4, stream);
  hipMemsetAsync(fill, 0, (size_t)Nn * 4, stream);

  for (int k = 0; k < 18; k++)
    hipMemcpyAsync(W + H_CUM[k], d_in[4 + k], (size_t)H_SZ[k] * 4,
                   hipMemcpyDeviceToDevice, stream);
  hipMemcpyAsync(h, x, (size_t)Nn * 64 * 4, hipMemcpyDeviceToDevice, stream);

  k_bnprep<<<2, 256, 0, stream>>>(W, bnAB);
  k_prep<<<(3*8704 + 255)/256, 256, 0, stream>>>(W, BswG);
  k_prep2<<<(3*65536 + 255)/256, 256, 0, stream>>>(W, Bsw2);
  k_prep3<<<(3*2048 + 255)/256, 256, 0, stream>>>(W, Wk1f);
  k_u<<<(Nn + 255)/256, 256, 0, stream>>>(posf, u);
  k_frame<<<(Nn + 255)/256, 256, 0, stream>>>(u, frame);
  k_edge<<<Ne/256, 256, 0, stream>>>(EI, posf, frame, et0, et1, et2, er0, er1, er2, cnt);
  k_scan1<<<SCAN_B, 1024, 0, stream>>>(cnt, locExc, btot);
  k_scan2<<<1, 64, 0, stream>>>(btot, boff, rowptr);
  k_scan3<<<(Nn + 255)/256, 256, 0, stream>>>(cnt, locExc, boff, rowptr, deginv);
  k_place<<<Ne/256, 256, 0, stream>>>(EI, EREL, rowptr, fill, yidx);

  for (int i = 0; i < Ll; i++) {
    const float* brel  = W + H_CUM[1]  + i * 64;
    const float* bself = W + H_CUM[3]  + i * 64;
    const float* Wl1   = W + H_CUM[4]  + i * 1024;
    const float* bl1   = W + H_CUM[5]  + i * 16;
    const float* bk1   = W + H_CUM[7]  + i * 32;
    const float* bk2   = W + H_CUM[9]  + i * 272;
    const float* Wl2   = W + H_CUM[10] + i * 1024;
    const float* bl2   = W + H_CUM[11] + i * 64;
    const float* lng   = W + H_CUM[16] + i * 64;
    const float* lnb   = W + H_CUM[17] + i * 64;
    const float* bnL   = bnAB + i * 320;
    const u16*   BswL  = BswG + i * 8704;

    hipMemsetAsync(moacc, 0, (size_t)Nn * 16 * 4, stream);
    k_rel2<<<(Nn + 63)/64, 256, 0, stream>>>(h, Bsw2 + i * 65536, brel, bself, Y, S);
    k_z<<<(Nn + 63)/64, 256, 0, stream>>>(h, Wl1, bl1, bk2, bnL, zt, biast);
    k_msg<<<Ne/256, 256, 0, stream>>>(et0, et1, et2, er0, er1, er2, EI,
                                      zt, biast, Wk1f + i * 2048, bk1, BswL, moacc);
    k_node<<<(Nn + 3)/4, 256, 0, stream>>>(h, S, Y, rowptr, yidx, moacc, deginv,
                                           Wl2, bl2, bnL, lng, lnb,
                                           (i == Ll - 1) ? outf : h);
  }
}

// Round 14
// 793.989 us; speedup vs baseline: 1.0106x; 1.0106x over previous
//
#include <hip/hip_runtime.h>
#include <hip/hip_bf16.h>

typedef unsigned short u16;
typedef unsigned int   u32;

static const int Nn  = 100000;
static const int Ne  = 800000;
static const int Ll  = 3;
static const int SCAN_B = 98;  // ceil(100000/1024)

typedef short     short8  __attribute__((ext_vector_type(8)));
typedef float     floatx4 __attribute__((ext_vector_type(4)));

// ---- cumulative f32-weight offsets (inputs 4..21 concatenated into W) ----
static const int H_CUM[19] = {
  0, 86016, 86208, 98496, 98688, 101760, 101808, 103152, 103248,
  129360, 130176, 133248, 133440, 134208, 134400, 134592, 135360, 135552, 135744
};
static const int H_SZ[18] = {
  86016, 192, 12288, 192, 3072, 48, 1344, 96,
  26112, 816, 3072, 192, 768, 192, 192, 768, 192, 192
};

union FU { u32 u; float f; };
__device__ __forceinline__ float b2f(u16 v) { FU x; x.u = ((u32)v) << 16; return x.f; }
__device__ __forceinline__ float lo2f(u32 w) { FU x; x.u = w << 16; return x.f; }
__device__ __forceinline__ float hi2f(u32 w) { FU x; x.u = w & 0xffff0000u; return x.f; }
__device__ __forceinline__ u16 f2b(float f) {
  FU x; x.f = f;
  u32 u = x.u;
  u32 r = (u + 0x7FFFu + ((u >> 16) & 1u)) >> 16;
  return (u16)r;
}
__device__ __forceinline__ u32 pk2(float a, float b) {
  __hip_bfloat162 h2 = __float22bfloat162_rn(make_float2(a, b));
  union { __hip_bfloat162 h; u32 u; } c; c.h = h2; return c.u;
}

// ---- fold BN (eval) into A*x+B per layer; layout per layer (320 f32) ----
__global__ void k_bnprep(const float* __restrict__ W, float* __restrict__ bnAB) {
  int idx = blockIdx.x * blockDim.x + threadIdx.x;
  if (idx >= 480) return;
  int i = idx / 160, d0 = idx % 160;
  const float* src; float* dstA; float* dstB; int dim, d;
  if (d0 < 64)       { d = d0;      src = W + 133440 + i * 256; dim = 64; dstA = bnAB + i*320 + 0;   dstB = bnAB + i*320 + 64;  }
  else if (d0 < 80)  { d = d0 - 64; src = W + 134208 + i * 64;  dim = 16; dstA = bnAB + i*320 + 128; dstB = bnAB + i*320 + 144; }
  else if (d0 < 96)  { d = d0 - 80; src = W + 134400 + i * 64;  dim = 16; dstA = bnAB + i*320 + 160; dstB = bnAB + i*320 + 176; }
  else               { d = d0 - 96; src = W + 134592 + i * 256; dim = 64; dstA = bnAB + i*320 + 192; dstB = bnAB + i*320 + 256; }
  float g = src[0*dim+d], b = src[1*dim+d], m = src[2*dim+d], v = src[3*dim+d];
  float A = g * rsqrtf(v + 1e-5f);
  float B = b - m * A;
  dstA[d] = A; dstB[d] = B;
}

// ---- Bsw prep: B-fragment-ordered bf16 Wk2 (for k_msg), K order flat = jp*32+q ----
__global__ void k_prep(const float* __restrict__ W, u16* __restrict__ BswG) {
  int i = blockIdx.x * 256 + threadIdx.x;
  if (i >= 3 * 8704) return;
  int layer = i / 8704, r = i % 8704;
  int jp = r / 512, l2 = r % 512;
  int lane = l2 / 8, j = l2 % 8;
  int q = (lane >> 4) * 8 + j, n = lane & 15;
  const float* Wk2 = W + 103248 + layer * 8704;
  BswG[i] = f2b(Wk2[q * 272 + jp * 16 + n]);
}

// ---- Bsw2 prep: B-fragment-ordered hi/lo bf16 [Wrel | Wself] for k_rel2 ----
__global__ void k_prep2(const float* __restrict__ W, u16* __restrict__ B2) {
  int idx = blockIdx.x * 256 + threadIdx.x;
  if (idx >= 3 * 65536) return;
  int layer = idx >> 16, r = idx & 65535;
  int fr = r >> 9;                 // 0..127 = nc*16 + nt*4 + ks*2 + hl
  int lane = (r >> 3) & 63, j = r & 7;
  int hl = fr & 1, ks = (fr >> 1) & 1, nt = (fr >> 2) & 3, nc = fr >> 4;
  int k = ks * 32 + (lane >> 4) * 8 + j;          // K index 0..63
  int g = nc * 64 + nt * 16 + (lane & 15);        // output col 0..511
  const float* Wrel  = W + layer * 28672;                  // H_CUM[0]
  const float* Wself = W + 86208 + layer * 4096;           // H_CUM[2]
  float v = (g < 448) ? Wrel[((g >> 6) * 64 + k) * 64 + (g & 63)]
                      : Wself[k * 64 + (g - 448)];
  u16 hi = f2b(v);
  B2[idx] = hl ? f2b(v - b2f(hi)) : hi;
}

// ---- Wk1 fragment prep for MFMA a-compute in k_msg ----
__global__ void k_prep3(const float* __restrict__ W, u16* __restrict__ Wk1f) {
  int idx = blockIdx.x * 256 + threadIdx.x;
  if (idx >= 3 * 2048) return;
  int layer = idx / 2048, r = idx % 2048;
  int kind = (r >> 10) & 1, nt = (r >> 9) & 1;
  int lane = (r >> 3) & 63, j = r & 7;
  int k = (lane >> 4) * 8 + j;
  int q = nt * 16 + (lane & 15);
  const float* Wk1 = W + 101808 + layer * 448;
  u16 out = 0;
  if (kind == 0) {
    if (k < 14)       out = f2b(Wk1[k * 32 + q]);
    else if (k < 28)  out = f2b(Wk1[(k - 14) * 32 + q]);
  } else {
    if (k < 14) {
      float w = Wk1[k * 32 + q];
      u16 hi = f2b(w);
      out = f2b(w - b2f(hi));
    }
  }
  Wk1f[idx] = out;
}

// ---- u[i] = normalize(pos[i]-pos[i-1]) ----
__global__ void k_u(const float* __restrict__ posf, float* __restrict__ u) {
  int i = blockIdx.x * blockDim.x + threadIdx.x;
  if (i >= Nn) return;
  float ux, uy, uz;
  if (i == 0) { ux = uy = uz = 0.57735026918962584f; }
  else {
    float vx = posf[i*3+0] - posf[(i-1)*3+0];
    float vy = posf[i*3+1] - posf[(i-1)*3+1];
    float vz = posf[i*3+2] - posf[(i-1)*3+2];
    float nrm = sqrtf(vx*vx + vy*vy + vz*vz);
    float inv = 1.0f / fmaxf(nrm, 1e-12f);
    ux = vx*inv; uy = vy*inv; uz = vz*inv;
  }
  u[i*3+0] = ux; u[i*3+1] = uy; u[i*3+2] = uz;
}

// ---- frame[i] = [b, n, cross(b,n)] stored [j*3+k] ----
__global__ void k_frame(const float* __restrict__ u, float* __restrict__ frame) {
  int i = blockIdx.x * blockDim.x + threadIdx.x;
  if (i >= Nn) return;
  float bx, by, bz, nx, ny, nz;
  if (i < Nn - 1) {
    float ax = u[i*3+0], ay = u[i*3+1], az = u[i*3+2];
    float cx = u[(i+1)*3+0], cy = u[(i+1)*3+1], cz = u[(i+1)*3+2];
    float dx = ax-cx, dy = ay-cy, dz = az-cz;
    float n1 = sqrtf(dx*dx + dy*dy + dz*dz);
    float i1 = 1.0f / fmaxf(n1, 1e-12f);
    bx = dx*i1; by = dy*i1; bz = dz*i1;
    float qx = ay*cz - az*cy, qy = az*cx - ax*cz, qz = ax*cy - ay*cx;
    float n2 = sqrtf(qx*qx + qy*qy + qz*qz);
    float i2 = 1.0f / fmaxf(n2, 1e-12f);
    nx = qx*i2; ny = qy*i2; nz = qz*i2;
  } else {
    bx = by = bz = 0.57735026918962584f;
    nx = ny = nz = 0.57735026918962584f;
  }
  float ex = by*nz - bz*ny, ey = bz*nx - bx*nz, ez = bx*ny - by*nx;
  frame[i*9+0] = bx; frame[i*9+1] = nx; frame[i*9+2] = ex;
  frame[i*9+3] = by; frame[i*9+4] = ny; frame[i*9+5] = ey;
  frame[i*9+6] = bz; frame[i*9+7] = nz; frame[i*9+8] = ez;
}

// ---- per-edge geometry (layer-invariant): t,r -> f32 SoA; + degree count ----
__global__ void k_edge(const int* __restrict__ EI, const float* __restrict__ posf,
                       const float* __restrict__ frame,
                       float* __restrict__ t0, float* __restrict__ t1, float* __restrict__ t2,
                       float* __restrict__ r0, float* __restrict__ r1, float* __restrict__ r2,
                       int* __restrict__ cnt) {
  int e = blockIdx.x * 256 + threadIdx.x;
  int vin = EI[e], vout = EI[Ne + e];
  float fi[9], fo[9];
#pragma unroll
  for (int t = 0; t < 9; t++) fi[t] = frame[(size_t)vin*9 + t];
#pragma unroll
  for (int t = 0; t < 9; t++) fo[t] = frame[(size_t)vout*9 + t];
  float d0 = posf[vout*3+0] - posf[vin*3+0];
  float d1 = posf[vout*3+1] - posf[vin*3+1];
  float d2 = posf[vout*3+2] - posf[vin*3+2];
  float tt[3], rr[3];
#pragma unroll
  for (int k = 0; k < 3; k++) {
    tt[k] = fi[0*3+k]*d0 + fi[1*3+k]*d1 + fi[2*3+k]*d2;
    rr[k] = fi[0*3+k]*fo[0*3+k] + fi[1*3+k]*fo[1*3+k] + fi[2*3+k]*fo[2*3+k];
  }
  t0[e] = tt[0]; t1[e] = tt[1]; t2[e] = tt[2];
  r0[e] = rr[0]; r1[e] = rr[1]; r2[e] = rr[2];
  atomicAdd(&cnt[vout], 1);
}

// ---- multi-block scan ----
__global__ __launch_bounds__(1024) void k_scan1(const int* __restrict__ cnt,
                                                int* __restrict__ locExc,
                                                int* __restrict__ btot) {
  __shared__ int sm[1024];
  int t = threadIdx.x, b = blockIdx.x;
  int i = b * 1024 + t;
  int v = (i < Nn) ? cnt[i] : 0;
  sm[t] = v;
  __syncthreads();
#pragma unroll
  for (int off = 1; off < 1024; off <<= 1) {
    int x = (t >= off) ? sm[t - off] : 0;
    __syncthreads();
    sm[t] += x;
    __syncthreads();
  }
  if (i < Nn) locExc[i] = sm[t] - v;
  if (t == 1023) btot[b] = sm[1023];
}

__global__ void k_scan2(const int* __restrict__ btot, int* __restrict__ boff,
                        int* __restrict__ rowptr) {
  if (threadIdx.x != 0 || blockIdx.x != 0) return;
  int run = 0;
  for (int b = 0; b < SCAN_B; b++) { boff[b] = run; run += btot[b]; }
  rowptr[Nn] = run;
}

__global__ void k_scan3(const int* __restrict__ cnt, const int* __restrict__ locExc,
                        const int* __restrict__ boff, int* __restrict__ rowptr,
                        float* __restrict__ deginv) {
  int i = blockIdx.x * blockDim.x + threadIdx.x;
  if (i >= Nn) return;
  rowptr[i] = locExc[i] + boff[i >> 10];
  int dv = cnt[i] > 1 ? cnt[i] : 1;
  deginv[i] = 1.0f / (float)dv;
}

// ---- place: CSR-ordered Y-offsets + inverse permutation ----
__global__ void k_place(const int* __restrict__ EI, const int* __restrict__ EREL,
                        const int* __restrict__ rowptr,
                        int* __restrict__ fill, int* __restrict__ yidx,
                        int* __restrict__ inv) {
  int e = blockIdx.x * blockDim.x + threadIdx.x;
  if (e >= Ne) return;
  int vout = EI[Ne + e];
  int p = atomicAdd(&fill[vout], 1);
  int slot = rowptr[vout] + p;
  inv[e] = slot;
  yidx[slot] = EI[e] * 448 + EREL[e] * 64;
}

// ---- MFMA rel: C[n, 0..511] = h[n,0..63] @ [Wrel(7) | Wself], hi/lo bf16 split ----
__global__ __launch_bounds__(256) void k_rel2(
    const float* __restrict__ h, const u16* __restrict__ Bsw,
    const float* __restrict__ brel, const float* __restrict__ bself,
    u16* __restrict__ Y, u16* __restrict__ S) {
  __shared__ uint4 bs4[1024];   // 16 KB: 16 frags x 64 uint4
  int tid = threadIdx.x;
  int w = tid >> 6, lane = tid & 63;
  int kq = lane >> 4, cl = lane & 15;
  int nb0 = blockIdx.x * 64;
  int anode = nb0 + w * 16 + cl;       // A-row node for this lane
  union U { uint4 u; short8 v; };

  // build A fragments (hi/lo) once: A[row=cl][k = ks*32 + kq*8 + j]
  uint4 Ah[2], Al[2];
#pragma unroll
  for (int ks = 0; ks < 2; ks++) {
    float p[8] = {0.f,0.f,0.f,0.f,0.f,0.f,0.f,0.f};
    if (anode < Nn) {
      const float4* hp = (const float4*)(h + (size_t)anode * 64 + ks * 32 + kq * 8);
      float4 q0 = hp[0], q1 = hp[1];
      p[0]=q0.x; p[1]=q0.y; p[2]=q0.z; p[3]=q0.w;
      p[4]=q1.x; p[5]=q1.y; p[6]=q1.z; p[7]=q1.w;
    }
    u32 hw[4], lw[4];
#pragma unroll
    for (int t = 0; t < 4; t++) {
      u16 ha = f2b(p[2*t]), hb = f2b(p[2*t+1]);
      hw[t] = (u32)ha | ((u32)hb << 16);
      lw[t] = pk2(p[2*t] - b2f(ha), p[2*t+1] - b2f(hb));
    }
    Ah[ks] = make_uint4(hw[0], hw[1], hw[2], hw[3]);
    Al[ks] = make_uint4(lw[0], lw[1], lw[2], lw[3]);
  }

  for (int nc = 0; nc < 8; nc++) {
    if (nc) __syncthreads();
    const uint4* src = (const uint4*)(Bsw + nc * 8192);
#pragma unroll
    for (int i = 0; i < 4; i++) bs4[tid + i * 256] = src[tid + i * 256];
    __syncthreads();

    floatx4 acc[4];
#pragma unroll
    for (int nt = 0; nt < 4; nt++) acc[nt] = (floatx4){0.f, 0.f, 0.f, 0.f};
#pragma unroll
    for (int nt = 0; nt < 4; nt++) {
#pragma unroll
      for (int ks = 0; ks < 2; ks++) {
        U bh, bl, ah, al;
        bh.u = bs4[((nt*2 + ks)*2 + 0)*64 + lane];
        bl.u = bs4[((nt*2 + ks)*2 + 1)*64 + lane];
        ah.u = Ah[ks]; al.u = Al[ks];
        acc[nt] = __builtin_amdgcn_mfma_f32_16x16x32_bf16(ah.v, bh.v, acc[nt], 0, 0, 0);
        acc[nt] = __builtin_amdgcn_mfma_f32_16x16x32_bf16(al.v, bh.v, acc[nt], 0, 0, 0);
        acc[nt] = __builtin_amdgcn_mfma_f32_16x16x32_bf16(ah.v, bl.v, acc[nt], 0, 0, 0);
      }
    }
    // D layout: col = lane&15, row = (lane>>4)*4 + reg
    if (nc < 7) {
#pragma unroll
      for (int nt = 0; nt < 4; nt++) {
#pragma unroll
        for (int reg = 0; reg < 4; reg++) {
          int node = nb0 + w * 16 + kq * 4 + reg;
          if (node < Nn)
            Y[(size_t)node * 448 + nc * 64 + nt * 16 + cl] = f2b(acc[nt][reg]);
        }
      }
    } else {
#pragma unroll
      for (int nt = 0; nt < 4; nt++) {
        int c = nt * 16 + cl;
        float bias = brel[c] + bself[c];
#pragma unroll
        for (int reg = 0; reg < 4; reg++) {
          int node = nb0 + w * 16 + kq * 4 + reg;
          if (node < Nn)
            S[(size_t)node * 64 + c] = f2b(acc[nt][reg] + bias);
        }
      }
    }
  }
}

// ---- per-node z + bias precompute ----
__global__ __launch_bounds__(256) void k_z(
    const float* __restrict__ h, const float* __restrict__ Wl1, const float* __restrict__ bl1,
    const float* __restrict__ bk2, const float* __restrict__ bn,
    u16* __restrict__ zt, u16* __restrict__ biast) {
  __shared__ float ls[64][65];
  __shared__ float zz[64][17];
  int tid = threadIdx.x;
  int nb0 = blockIdx.x * 64;
  const float* Ain = bn + 0;
  const float* Bin = bn + 64;
#pragma unroll
  for (int r = 0; r < 16; r++) {
    int idx = r * 256 + tid;
    int row = idx >> 6, col = idx & 63;
    int node = nb0 + row;
    float v = (node < Nn) ? h[(size_t)node * 64 + col] : 0.0f;
    ls[row][col] = fmaxf(v * Ain[col] + Bin[col], 0.0f);
  }
  __syncthreads();
  int row = tid >> 2, jq = (tid & 3) * 4;
  int node = nb0 + row;
  const float* Amsg = bn + 128;
  const float* Bmsg = bn + 144;
  float m1[4];
#pragma unroll
  for (int t = 0; t < 4; t++) m1[t] = bl1[jq + t];
  for (int c = 0; c < 64; c++) {
    float lv = ls[row][c];
#pragma unroll
    for (int t = 0; t < 4; t++) m1[t] += lv * Wl1[c * 16 + jq + t];
  }
  float zv[4];
#pragma unroll
  for (int t = 0; t < 4; t++) {
    zv[t] = fmaxf(m1[t] * Amsg[jq + t] + Bmsg[jq + t], 0.0f);
    zz[row][jq + t] = zv[t];
  }
  if (node < Nn) {
    u32* zg = (u32*)zt + (size_t)node * 8 + (tid & 3) * 2;
    zg[0] = pk2(zv[0], zv[1]);
    zg[1] = pk2(zv[2], zv[3]);
  }
  __syncthreads();
  float bb[4];
#pragma unroll
  for (int t = 0; t < 4; t++) bb[t] = bk2[jq + t];
  for (int j = 0; j < 16; j++) {
    float zj = zz[row][j];
#pragma unroll
    for (int t = 0; t < 4; t++) bb[t] += zj * bk2[(j + 1) * 16 + jq + t];
  }
  if (node < Nn) {
    u32* bg = (u32*)biast + (size_t)node * 8 + (tid & 3) * 2;
    bg[0] = pk2(bb[0], bb[1]);
    bg[1] = pk2(bb[2], bb[3]);
  }
}

// ---- per-edge MFMA kernel: B frags direct from L2 (no LDS staging) ----
__global__ __launch_bounds__(256) void k_msg(
    const float* __restrict__ t0, const float* __restrict__ t1, const float* __restrict__ t2,
    const float* __restrict__ r0, const float* __restrict__ r1, const float* __restrict__ r2,
    const int* __restrict__ EI, const int* __restrict__ inv,
    const u16* __restrict__ zt, const u16* __restrict__ biast,
    const u16* __restrict__ Wk1f, const float* __restrict__ bk1,
    const u16* __restrict__ BswG, u16* __restrict__ mo) {
  __shared__ u16 abuf[256 * 40];   // ef->a rows, stride 40 u16 (80 B) -> 20480 B
  __shared__ int ivin[256];        // 1024 B  (total 21504 B -> 7 blocks/CU)

  int tid = threadIdx.x;
  int e0 = blockIdx.x * 256;
  int e = e0 + tid;

  int vin = EI[e], vout = EI[Ne + e];
  ivin[tid] = vin;

  float ef[14];
  ef[0] = t0[e]; ef[1] = t1[e]; ef[2] = t2[e];
  ef[3] = r0[e]; ef[4] = r1[e]; ef[5] = r2[e];
  int ad = vin - vout; if (ad < 0) ad = -ad;
  ef[6] = ((float)ad) / 6.0f;
#pragma unroll
  for (int k = 0; k < 7; k++) ef[7+k] = 1.0f - 2.0f*fabsf(ef[k]);

  // pack ef hi/lo A-row: k=0..13 hi, 14..27 lo, 28..31 zero
  u16 row[32];
#pragma unroll
  for (int d = 0; d < 14; d++) {
    u16 hi = f2b(ef[d]);
    row[d] = hi;
    row[14 + d] = f2b(ef[d] - b2f(hi));
  }
#pragma unroll
  for (int d = 28; d < 32; d++) row[d] = 0;
  u32* ar = (u32*)(abuf + (size_t)tid * 40);
#pragma unroll
  for (int i = 0; i < 16; i++)
    ar[i] = (u32)row[2*i] | ((u32)row[2*i+1] << 16);
  __syncthreads();

  int lane = tid & 63, w4 = (tid >> 6) * 4;
  int m = lane & 15, quad = lane >> 4;
  union U { uint4 u; short8 v; };

  // a-GEMM B fragments (global, tiny L2-hot table) + bk1 per output col
  U b0[2], b1[2];
#pragma unroll
  for (int nt = 0; nt < 2; nt++) {
    b0[nt].u = *(const uint4*)(Wk1f + 0*1024 + nt*512 + lane*8);
    b1[nt].u = *(const uint4*)(Wk1f + 1*1024 + nt*512 + lane*8);
  }
  float bk1v[2] = { bk1[m], bk1[16 + m] };
  const u16* bswL = BswG + (size_t)lane * 8;   // per-lane base into B-frag table

#pragma unroll
  for (int t = 0; t < 4; t++) {
    int s0 = (w4 + t) * 16;
    const u16* rs0 = abuf + (size_t)(s0 + m) * 40;

    // ---- a = relu(ef @ Wk1 + bk1) via 2x2 MFMAs, written back in place ----
    U efr; efr.u = *(const uint4*)(rs0 + quad * 8);
#pragma unroll
    for (int nt = 0; nt < 2; nt++) {
      floatx4 aa = {0.f, 0.f, 0.f, 0.f};
      aa = __builtin_amdgcn_mfma_f32_16x16x32_bf16(efr.v, b0[nt].v, aa, 0, 0, 0);
      aa = __builtin_amdgcn_mfma_f32_16x16x32_bf16(efr.v, b1[nt].v, aa, 0, 0, 0);
#pragma unroll
      for (int reg = 0; reg < 4; reg++) {
        int se = s0 + quad * 4 + reg;
        float av = fmaxf(aa[reg] + bk1v[nt], 0.0f);
        abuf[(size_t)se * 40 + nt * 16 + m] = f2b(av);
      }
    }
    U afr; afr.u = *(const uint4*)(rs0 + quad * 8);   // re-read: now 'a'

    // ---- row metadata: z (2x uint4), bias, out slot for the 4 owned rows ----
    int se0 = s0 + quad * 4;
    uint4 z0[4], z1[4]; float bv[4]; int sl[4];
#pragma unroll
    for (int reg = 0; reg < 4; reg++) {
      int vi = ivin[se0 + reg];
      const uint4* zp = (const uint4*)(zt + (size_t)vi * 16);
      z0[reg] = zp[0]; z1[reg] = zp[1];
      bv[reg] = b2f(biast[(size_t)vi * 16 + m]);
      sl[reg] = inv[e0 + se0 + reg];
    }

    // ---- ker MFMAs (B frags from L2) with immediate per-jp consume ----
    float acc[4];
    {
      U bfr; bfr.u = *(const uint4*)(bswL);
      floatx4 zz4 = {0.f, 0.f, 0.f, 0.f};
      floatx4 k0 = __builtin_amdgcn_mfma_f32_16x16x32_bf16(afr.v, bfr.v, zz4, 0, 0, 0);
#pragma unroll
      for (int reg = 0; reg < 4; reg++) acc[reg] = k0[reg];
    }
#pragma unroll
    for (int jp = 1; jp <= 16; jp++) {
      U bfr; bfr.u = *(const uint4*)(bswL + (size_t)jp * 512);
      floatx4 zz4 = {0.f, 0.f, 0.f, 0.f};
      floatx4 kj = __builtin_amdgcn_mfma_f32_16x16x32_bf16(afr.v, bfr.v, zz4, 0, 0, 0);
      const int zi = jp - 1;
#pragma unroll
      for (int reg = 0; reg < 4; reg++) {
        const u32* zw = (zi < 8) ? (const u32*)&z0[reg] : (const u32*)&z1[reg];
        u32 wv = zw[(zi & 7) >> 1];
        float zv = (zi & 1) ? hi2f(wv) : lo2f(wv);
        acc[reg] += zv * kj[reg];
      }
    }
#pragma unroll
    for (int reg = 0; reg < 4; reg++)
      mo[(size_t)sl[reg] * 16 + m] = f2b(acc[reg] + bv[reg]);
  }
}

// ---- per-node: 2x-unrolled (8 edges in flight) Y gather + mo sum, residual, LN ----
__global__ __launch_bounds__(256) void k_node(
    const float* __restrict__ h, const u16* __restrict__ S, const u16* __restrict__ Y,
    const int* __restrict__ rowptr, const int* __restrict__ yidx,
    const u16* __restrict__ mo, const float* __restrict__ deginv,
    const float* __restrict__ Wl2, const float* __restrict__ bl2,
    const float* __restrict__ bn, const float* __restrict__ lng, const float* __restrict__ lnb,
    float* __restrict__ hout) {
  __shared__ float relsm[4][64];
  __shared__ float u2s[4][16];
  int tid = threadIdx.x;
  int lane = tid & 63, w = tid >> 6;
  int n = blockIdx.x * 4 + w;
  bool act = (n < Nn);

  if (act) {
    int beg = rowptr[n], end = rowptr[n+1];

    // ---- part A: rel sum over Y rows; 2 rounds unrolled -> 2 loads in flight ----
    int g = lane >> 4, col4 = lane & 15;
    float a4[4] = {0.f, 0.f, 0.f, 0.f};
    for (int c0 = beg; c0 < end; c0 += 64) {
      int l = c0 + lane;
      int yo = (l < end) ? yidx[l] : 0;
      int cnt = end - c0; if (cnt > 64) cnt = 64;
      for (int j0 = 0; j0 < cnt; j0 += 8) {
        int jA = j0 + g;
        int jB = j0 + 4 + g;
        int yA = __shfl(yo, jA, 64);
        int yB = __shfl(yo, jB, 64);
        bool vA = (jA < cnt), vB = (jB < cnt);
        uint2 dA = vA ? *(const uint2*)(Y + (size_t)yA + col4 * 4) : make_uint2(0u, 0u);
        uint2 dB = vB ? *(const uint2*)(Y + (size_t)yB + col4 * 4) : make_uint2(0u, 0u);
        a4[0] += lo2f(dA.x); a4[1] += hi2f(dA.x);
        a4[2] += lo2f(dA.y); a4[3] += hi2f(dA.y);
        a4[0] += lo2f(dB.x); a4[1] += hi2f(dB.x);
        a4[2] += lo2f(dB.y); a4[3] += hi2f(dB.y);
      }
    }
#pragma unroll
    for (int t = 0; t < 4; t++) {
      a4[t] += __shfl_xor(a4[t], 16, 64);
      a4[t] += __shfl_xor(a4[t], 32, 64);
    }
    if (lane < 16) {
#pragma unroll
      for (int t = 0; t < 4; t++) relsm[w][col4 * 4 + t] = a4[t];
    }

    // ---- part B: mo sum, 16 CSR slots per round (row=lane>>2, uint2/lane) ----
    int r = lane >> 2, c4 = lane & 3;
    float p4[4] = {0.f, 0.f, 0.f, 0.f};
    for (int p0 = beg; p0 < end; p0 += 16) {
      int p = p0 + r;
      if (p < end) {
        uint2 d = *(const uint2*)(mo + (size_t)p * 16 + c4 * 4);
        p4[0] += lo2f(d.x); p4[1] += hi2f(d.x);
        p4[2] += lo2f(d.y); p4[3] += hi2f(d.y);
      }
    }
#pragma unroll
    for (int t = 0; t < 4; t++) {
      p4[t] += __shfl_xor(p4[t],  4, 64);
      p4[t] += __shfl_xor(p4[t],  8, 64);
      p4[t] += __shfl_xor(p4[t], 16, 64);
      p4[t] += __shfl_xor(p4[t], 32, 64);
    }
    const float* Aupd = bn + 160;
    const float* Bupd = bn + 176;
    if (lane < 4) {
      float di = deginv[n];
#pragma unroll
      for (int t = 0; t < 4; t++) {
        int col = c4 * 4 + t;
        float v = p4[t] * di;
        u2s[w][col] = fmaxf(v * Aupd[col] + Bupd[col], 0.0f);
      }
    }
  }
  __syncthreads();
  if (act) {
    float rel_out = fmaxf(b2f(S[(size_t)n*64 + lane]) + relsm[w][lane], 0.0f);
    float ie = bl2[lane];
#pragma unroll
    for (int j = 0; j < 16; j++) ie += u2s[w][j] * Wl2[j*64 + lane];
    const float* Aout = bn + 192;
    const float* Bout = bn + 256;
    ie = ie * Aout[lane] + Bout[lane];
    float hidden = rel_out + ie + h[(size_t)n*64 + lane];
    float s = hidden;
#pragma unroll
    for (int off = 32; off > 0; off >>= 1) s += __shfl_xor(s, off, 64);
    float mu = s * (1.0f/64.0f);
    float d = hidden - mu;
    float s2 = d * d;
#pragma unroll
    for (int off = 32; off > 0; off >>= 1) s2 += __shfl_xor(s2, off, 64);
    float var = s2 * (1.0f/64.0f);
    float o = d * rsqrtf(var + 1e-5f) * lng[lane] + lnb[lane];
    hout[(size_t)n*64 + lane] = o;
  }
}

extern "C" void kernel_launch(void* const* d_in, const int* in_sizes, int n_in,
                              void* d_out, int out_size, void* d_ws, size_t ws_size,
                              hipStream_t stream) {
  const float* x    = (const float*)d_in[0];
  const float* posf = (const float*)d_in[1];
  const int* EI     = (const int*)d_in[2];
  const int* EREL   = (const int*)d_in[3];
  float* outf       = (float*)d_out;

  char* p = (char*)d_ws;
  auto alloc = [&](size_t bytes) -> char* {
    char* r = p;
    p += (bytes + 255) & ~((size_t)255);
    return r;
  };
  float* W      = (float*)alloc((size_t)135744 * 4);
  float* bnAB   = (float*)alloc((size_t)960 * 4);
  u16*   BswG   = (u16*)  alloc((size_t)3 * 8704 * 2);
  u16*   Bsw2   = (u16*)  alloc((size_t)3 * 65536 * 2);
  u16*   Wk1f   = (u16*)  alloc((size_t)3 * 2048 * 2);
  float* u      = (float*)alloc((size_t)Nn * 3 * 4);
  float* frame  = (float*)alloc((size_t)Nn * 9 * 4);
  int*   cnt    = (int*)  alloc((size_t)Nn * 4);
  int*   fill   = (int*)  alloc((size_t)Nn * 4);
  int*   rowptr = (int*)  alloc((size_t)(Nn + 1) * 4);
  int*   locExc = (int*)  alloc((size_t)Nn * 4);
  int*   btot   = (int*)  alloc((size_t)SCAN_B * 4);
  int*   boff   = (int*)  alloc((size_t)SCAN_B * 4);
  int*   yidx   = (int*)  alloc((size_t)Ne * 4);
  int*   inv    = (int*)  alloc((size_t)Ne * 4);
  float* deginv = (float*)alloc((size_t)Nn * 4);
  float* h      = (float*)alloc((size_t)Nn * 64 * 4);
  u16*   S      = (u16*)  alloc((size_t)Nn * 64 * 2);
  u16*   Y      = (u16*)  alloc((size_t)Nn * 448 * 2);
  u16*   mo     = (u16*)  alloc((size_t)Ne * 16 * 2);
  u16*   zt     = (u16*)  alloc((size_t)Nn * 16 * 2);
  u16*   biast  = (u16*)  alloc((size_t)Nn * 16 * 2);
  float* et0    = (float*)alloc((size_t)Ne * 4);
  float* et1    = (float*)alloc((size_t)Ne * 4);
  float* et2    = (float*)alloc((size_t)Ne * 4);
  float* er0    = (float*)alloc((size_t)Ne * 4);
  float* er1    = (float*)alloc((size_t)Ne * 4);
  float* er2    = (float*)alloc((size_t)Ne * 4);
  (void)n_in; (void)in_sizes; (void)out_size;

  size_t needed = (size_t)(p - (char*)d_ws);
  if (needed > ws_size) return;  // diagnostic: zero output => absmax == max|ref| (~4.75)

  hipMemsetAsync(cnt,  0, (size_t)Nn * 4, stream);
  hipMemsetAsync(fill, 0, (size_t)Nn * 4, stream);

  for (int k = 0; k < 18; k++)
    hipMemcpyAsync(W + H_CUM[k], d_in[4 + k], (size_t)H_SZ[k] * 4,
                   hipMemcpyDeviceToDevice, stream);
  hipMemcpyAsync(h, x, (size_t)Nn * 64 * 4, hipMemcpyDeviceToDevice, stream);

  k_bnprep<<<2, 256, 0, stream>>>(W, bnAB);
  k_prep<<<(3*8704 + 255)/256, 256, 0, stream>>>(W, BswG);
  k_prep2<<<(3*65536 + 255)/256, 256, 0, stream>>>(W, Bsw2);
  k_prep3<<<(3*2048 + 255)/256, 256, 0, stream>>>(W, Wk1f);
  k_u<<<(Nn + 255)/256, 256, 0, stream>>>(posf, u);
  k_frame<<<(Nn + 255)/256, 256, 0, stream>>>(u, frame);
  k_edge<<<Ne/256, 256, 0, stream>>>(EI, posf, frame, et0, et1, et2, er0, er1, er2, cnt);
  k_scan1<<<SCAN_B, 1024, 0, stream>>>(cnt, locExc, btot);
  k_scan2<<<1, 64, 0, stream>>>(btot, boff, rowptr);
  k_scan3<<<(Nn + 255)/256, 256, 0, stream>>>(cnt, locExc, boff, rowptr, deginv);
  k_place<<<Ne/256, 256, 0, stream>>>(EI, EREL, rowptr, fill, yidx, inv);

  for (int i = 0; i < Ll; i++) {
    const float* brel  = W + H_CUM[1]  + i * 64;
    const float* bself = W + H_CUM[3]  + i * 64;
    const float* Wl1   = W + H_CUM[4]  + i * 1024;
    const float* bl1   = W + H_CUM[5]  + i * 16;
    const float* bk1   = W + H_CUM[7]  + i * 32;
    const float* bk2   = W + H_CUM[9]  + i * 272;
    const float* Wl2   = W + H_CUM[10] + i * 1024;
    const float* bl2   = W + H_CUM[11] + i * 64;
    const float* lng   = W + H_CUM[16] + i * 64;
    const float* lnb   = W + H_CUM[17] + i * 64;
    const float* bnL   = bnAB + i * 320;
    const u16*   BswL  = BswG + i * 8704;

    k_rel2<<<(Nn + 63)/64, 256, 0, stream>>>(h, Bsw2 + i * 65536, brel, bself, Y, S);
    k_z<<<(Nn + 63)/64, 256, 0, stream>>>(h, Wl1, bl1, bk2, bnL, zt, biast);
    k_msg<<<Ne/256, 256, 0, stream>>>(et0, et1, et2, er0, er1, er2, EI, inv,
                                      zt, biast, Wk1f + i * 2048, bk1, BswL, mo);
    k_node<<<(Nn + 3)/4, 256, 0, stream>>>(h, S, Y, rowptr, yidx, mo, deginv,
                                           Wl2, bl2, bnL, lng, lnb,
                                           (i == Ll - 1) ? outf : h);
  }
}

// Round 15
// 788.693 us; speedup vs baseline: 1.0174x; 1.0067x over previous
//
#include <hip/hip_runtime.h>
#include <hip/hip_bf16.h>

typedef unsigned short u16;
typedef unsigned int   u32;

static const int Nn  = 100000;
static const int Ne  = 800000;
static const int Ll  = 3;
static const int SCAN_B = 98;  // ceil(100000/1024)

typedef short     short8  __attribute__((ext_vector_type(8)));
typedef float     floatx4 __attribute__((ext_vector_type(4)));

// ---- cumulative f32-weight offsets (inputs 4..21 concatenated into W) ----
static const int H_CUM[19] = {
  0, 86016, 86208, 98496, 98688, 101760, 101808, 103152, 103248,
  129360, 130176, 133248, 133440, 134208, 134400, 134592, 135360, 135552, 135744
};
static const int H_SZ[18] = {
  86016, 192, 12288, 192, 3072, 48, 1344, 96,
  26112, 816, 3072, 192, 768, 192, 192, 768, 192, 192
};

union FU { u32 u; float f; };
__device__ __forceinline__ float b2f(u16 v) { FU x; x.u = ((u32)v) << 16; return x.f; }
__device__ __forceinline__ float lo2f(u32 w) { FU x; x.u = w << 16; return x.f; }
__device__ __forceinline__ float hi2f(u32 w) { FU x; x.u = w & 0xffff0000u; return x.f; }
__device__ __forceinline__ u16 f2b(float f) {
  FU x; x.f = f;
  u32 u = x.u;
  u32 r = (u + 0x7FFFu + ((u >> 16) & 1u)) >> 16;
  return (u16)r;
}
__device__ __forceinline__ u32 pk2(float a, float b) {
  __hip_bfloat162 h2 = __float22bfloat162_rn(make_float2(a, b));
  union { __hip_bfloat162 h; u32 u; } c; c.h = h2; return c.u;
}

// ---- fold BN (eval) into A*x+B per layer; layout per layer (320 f32) ----
__global__ void k_bnprep(const float* __restrict__ W, float* __restrict__ bnAB) {
  int idx = blockIdx.x * blockDim.x + threadIdx.x;
  if (idx >= 480) return;
  int i = idx / 160, d0 = idx % 160;
  const float* src; float* dstA; float* dstB; int dim, d;
  if (d0 < 64)       { d = d0;      src = W + 133440 + i * 256; dim = 64; dstA = bnAB + i*320 + 0;   dstB = bnAB + i*320 + 64;  }
  else if (d0 < 80)  { d = d0 - 64; src = W + 134208 + i * 64;  dim = 16; dstA = bnAB + i*320 + 128; dstB = bnAB + i*320 + 144; }
  else if (d0 < 96)  { d = d0 - 80; src = W + 134400 + i * 64;  dim = 16; dstA = bnAB + i*320 + 160; dstB = bnAB + i*320 + 176; }
  else               { d = d0 - 96; src = W + 134592 + i * 256; dim = 64; dstA = bnAB + i*320 + 192; dstB = bnAB + i*320 + 256; }
  float g = src[0*dim+d], b = src[1*dim+d], m = src[2*dim+d], v = src[3*dim+d];
  float A = g * rsqrtf(v + 1e-5f);
  float B = b - m * A;
  dstA[d] = A; dstB[d] = B;
}

// ---- Bsw prep: B-fragment-ordered bf16 Wk2 (for k_msg), K order flat = jp*32+q ----
__global__ void k_prep(const float* __restrict__ W, u16* __restrict__ BswG) {
  int i = blockIdx.x * 256 + threadIdx.x;
  if (i >= 3 * 8704) return;
  int layer = i / 8704, r = i % 8704;
  int jp = r / 512, l2 = r % 512;
  int lane = l2 / 8, j = l2 % 8;
  int q = (lane >> 4) * 8 + j, n = lane & 15;
  const float* Wk2 = W + 103248 + layer * 8704;
  BswG[i] = f2b(Wk2[q * 272 + jp * 16 + n]);
}

// ---- Bsw2 prep: B-fragment-ordered hi/lo bf16 [Wrel | Wself] for k_rel2 ----
__global__ void k_prep2(const float* __restrict__ W, u16* __restrict__ B2) {
  int idx = blockIdx.x * 256 + threadIdx.x;
  if (idx >= 3 * 65536) return;
  int layer = idx >> 16, r = idx & 65535;
  int fr = r >> 9;                 // 0..127 = nc*16 + nt*4 + ks*2 + hl
  int lane = (r >> 3) & 63, j = r & 7;
  int hl = fr & 1, ks = (fr >> 1) & 1, nt = (fr >> 2) & 3, nc = fr >> 4;
  int k = ks * 32 + (lane >> 4) * 8 + j;          // K index 0..63
  int g = nc * 64 + nt * 16 + (lane & 15);        // output col 0..511
  const float* Wrel  = W + layer * 28672;                  // H_CUM[0]
  const float* Wself = W + 86208 + layer * 4096;           // H_CUM[2]
  float v = (g < 448) ? Wrel[((g >> 6) * 64 + k) * 64 + (g & 63)]
                      : Wself[k * 64 + (g - 448)];
  u16 hi = f2b(v);
  B2[idx] = hl ? f2b(v - b2f(hi)) : hi;
}

// ---- Wk1 fragment prep for MFMA a-compute in k_msg ----
__global__ void k_prep3(const float* __restrict__ W, u16* __restrict__ Wk1f) {
  int idx = blockIdx.x * 256 + threadIdx.x;
  if (idx >= 3 * 2048) return;
  int layer = idx / 2048, r = idx % 2048;
  int kind = (r >> 10) & 1, nt = (r >> 9) & 1;
  int lane = (r >> 3) & 63, j = r & 7;
  int k = (lane >> 4) * 8 + j;
  int q = nt * 16 + (lane & 15);
  const float* Wk1 = W + 101808 + layer * 448;
  u16 out = 0;
  if (kind == 0) {
    if (k < 14)       out = f2b(Wk1[k * 32 + q]);
    else if (k < 28)  out = f2b(Wk1[(k - 14) * 32 + q]);
  } else {
    if (k < 14) {
      float w = Wk1[k * 32 + q];
      u16 hi = f2b(w);
      out = f2b(w - b2f(hi));
    }
  }
  Wk1f[idx] = out;
}

// ---- u[i] = normalize(pos[i]-pos[i-1]) ----
__global__ void k_u(const float* __restrict__ posf, float* __restrict__ u) {
  int i = blockIdx.x * blockDim.x + threadIdx.x;
  if (i >= Nn) return;
  float ux, uy, uz;
  if (i == 0) { ux = uy = uz = 0.57735026918962584f; }
  else {
    float vx = posf[i*3+0] - posf[(i-1)*3+0];
    float vy = posf[i*3+1] - posf[(i-1)*3+1];
    float vz = posf[i*3+2] - posf[(i-1)*3+2];
    float nrm = sqrtf(vx*vx + vy*vy + vz*vz);
    float inv = 1.0f / fmaxf(nrm, 1e-12f);
    ux = vx*inv; uy = vy*inv; uz = vz*inv;
  }
  u[i*3+0] = ux; u[i*3+1] = uy; u[i*3+2] = uz;
}

// ---- frame[i] = [b, n, cross(b,n)] stored [j*3+k] ----
__global__ void k_frame(const float* __restrict__ u, float* __restrict__ frame) {
  int i = blockIdx.x * blockDim.x + threadIdx.x;
  if (i >= Nn) return;
  float bx, by, bz, nx, ny, nz;
  if (i < Nn - 1) {
    float ax = u[i*3+0], ay = u[i*3+1], az = u[i*3+2];
    float cx = u[(i+1)*3+0], cy = u[(i+1)*3+1], cz = u[(i+1)*3+2];
    float dx = ax-cx, dy = ay-cy, dz = az-cz;
    float n1 = sqrtf(dx*dx + dy*dy + dz*dz);
    float i1 = 1.0f / fmaxf(n1, 1e-12f);
    bx = dx*i1; by = dy*i1; bz = dz*i1;
    float qx = ay*cz - az*cy, qy = az*cx - ax*cz, qz = ax*cy - ay*cx;
    float n2 = sqrtf(qx*qx + qy*qy + qz*qz);
    float i2 = 1.0f / fmaxf(n2, 1e-12f);
    nx = qx*i2; ny = qy*i2; nz = qz*i2;
  } else {
    bx = by = bz = 0.57735026918962584f;
    nx = ny = nz = 0.57735026918962584f;
  }
  float ex = by*nz - bz*ny, ey = bz*nx - bx*nz, ez = bx*ny - by*nx;
  frame[i*9+0] = bx; frame[i*9+1] = nx; frame[i*9+2] = ex;
  frame[i*9+3] = by; frame[i*9+4] = ny; frame[i*9+5] = ey;
  frame[i*9+6] = bz; frame[i*9+7] = nz; frame[i*9+8] = ez;
}

// ---- per-edge geometry (layer-invariant): t,r -> f32 SoA; + degree count ----
__global__ void k_edge(const int* __restrict__ EI, const float* __restrict__ posf,
                       const float* __restrict__ frame,
                       float* __restrict__ t0, float* __restrict__ t1, float* __restrict__ t2,
                       float* __restrict__ r0, float* __restrict__ r1, float* __restrict__ r2,
                       int* __restrict__ cnt) {
  int e = blockIdx.x * 256 + threadIdx.x;
  int vin = EI[e], vout = EI[Ne + e];
  float fi[9], fo[9];
#pragma unroll
  for (int t = 0; t < 9; t++) fi[t] = frame[(size_t)vin*9 + t];
#pragma unroll
  for (int t = 0; t < 9; t++) fo[t] = frame[(size_t)vout*9 + t];
  float d0 = posf[vout*3+0] - posf[vin*3+0];
  float d1 = posf[vout*3+1] - posf[vin*3+1];
  float d2 = posf[vout*3+2] - posf[vin*3+2];
  float tt[3], rr[3];
#pragma unroll
  for (int k = 0; k < 3; k++) {
    tt[k] = fi[0*3+k]*d0 + fi[1*3+k]*d1 + fi[2*3+k]*d2;
    rr[k] = fi[0*3+k]*fo[0*3+k] + fi[1*3+k]*fo[1*3+k] + fi[2*3+k]*fo[2*3+k];
  }
  t0[e] = tt[0]; t1[e] = tt[1]; t2[e] = tt[2];
  r0[e] = rr[0]; r1[e] = rr[1]; r2[e] = rr[2];
  atomicAdd(&cnt[vout], 1);
}

// ---- multi-block scan ----
__global__ __launch_bounds__(1024) void k_scan1(const int* __restrict__ cnt,
                                                int* __restrict__ locExc,
                                                int* __restrict__ btot) {
  __shared__ int sm[1024];
  int t = threadIdx.x, b = blockIdx.x;
  int i = b * 1024 + t;
  int v = (i < Nn) ? cnt[i] : 0;
  sm[t] = v;
  __syncthreads();
#pragma unroll
  for (int off = 1; off < 1024; off <<= 1) {
    int x = (t >= off) ? sm[t - off] : 0;
    __syncthreads();
    sm[t] += x;
    __syncthreads();
  }
  if (i < Nn) locExc[i] = sm[t] - v;
  if (t == 1023) btot[b] = sm[1023];
}

__global__ void k_scan2(const int* __restrict__ btot, int* __restrict__ boff,
                        int* __restrict__ rowptr) {
  if (threadIdx.x != 0 || blockIdx.x != 0) return;
  int run = 0;
  for (int b = 0; b < SCAN_B; b++) { boff[b] = run; run += btot[b]; }
  rowptr[Nn] = run;
}

__global__ void k_scan3(const int* __restrict__ cnt, const int* __restrict__ locExc,
                        const int* __restrict__ boff, int* __restrict__ rowptr,
                        float* __restrict__ deginv) {
  int i = blockIdx.x * blockDim.x + threadIdx.x;
  if (i >= Nn) return;
  rowptr[i] = locExc[i] + boff[i >> 10];
  int dv = cnt[i] > 1 ? cnt[i] : 1;
  deginv[i] = 1.0f / (float)dv;
}

// ---- place: CSR-ordered Y-offsets + inverse permutation ----
__global__ void k_place(const int* __restrict__ EI, const int* __restrict__ EREL,
                        const int* __restrict__ rowptr,
                        int* __restrict__ fill, int* __restrict__ yidx,
                        int* __restrict__ inv) {
  int e = blockIdx.x * blockDim.x + threadIdx.x;
  if (e >= Ne) return;
  int vout = EI[Ne + e];
  int p = atomicAdd(&fill[vout], 1);
  int slot = rowptr[vout] + p;
  inv[e] = slot;
  yidx[slot] = EI[e] * 448 + EREL[e] * 64;
}

// ---- MFMA rel: C[n, 0..511] = h[n,0..63] @ [Wrel(7) | Wself], hi/lo bf16 split ----
__global__ __launch_bounds__(256) void k_rel2(
    const float* __restrict__ h, const u16* __restrict__ Bsw,
    const float* __restrict__ brel, const float* __restrict__ bself,
    u16* __restrict__ Y, u16* __restrict__ S) {
  __shared__ uint4 bs4[1024];   // 16 KB: 16 frags x 64 uint4
  int tid = threadIdx.x;
  int w = tid >> 6, lane = tid & 63;
  int kq = lane >> 4, cl = lane & 15;
  int nb0 = blockIdx.x * 64;
  int anode = nb0 + w * 16 + cl;       // A-row node for this lane
  union U { uint4 u; short8 v; };

  // build A fragments (hi/lo) once: A[row=cl][k = ks*32 + kq*8 + j]
  uint4 Ah[2], Al[2];
#pragma unroll
  for (int ks = 0; ks < 2; ks++) {
    float p[8] = {0.f,0.f,0.f,0.f,0.f,0.f,0.f,0.f};
    if (anode < Nn) {
      const float4* hp = (const float4*)(h + (size_t)anode * 64 + ks * 32 + kq * 8);
      float4 q0 = hp[0], q1 = hp[1];
      p[0]=q0.x; p[1]=q0.y; p[2]=q0.z; p[3]=q0.w;
      p[4]=q1.x; p[5]=q1.y; p[6]=q1.z; p[7]=q1.w;
    }
    u32 hw[4], lw[4];
#pragma unroll
    for (int t = 0; t < 4; t++) {
      u16 ha = f2b(p[2*t]), hb = f2b(p[2*t+1]);
      hw[t] = (u32)ha | ((u32)hb << 16);
      lw[t] = pk2(p[2*t] - b2f(ha), p[2*t+1] - b2f(hb));
    }
    Ah[ks] = make_uint4(hw[0], hw[1], hw[2], hw[3]);
    Al[ks] = make_uint4(lw[0], lw[1], lw[2], lw[3]);
  }

  for (int nc = 0; nc < 8; nc++) {
    if (nc) __syncthreads();
    const uint4* src = (const uint4*)(Bsw + nc * 8192);
#pragma unroll
    for (int i = 0; i < 4; i++) bs4[tid + i * 256] = src[tid + i * 256];
    __syncthreads();

    floatx4 acc[4];
#pragma unroll
    for (int nt = 0; nt < 4; nt++) acc[nt] = (floatx4){0.f, 0.f, 0.f, 0.f};
#pragma unroll
    for (int nt = 0; nt < 4; nt++) {
#pragma unroll
      for (int ks = 0; ks < 2; ks++) {
        U bh, bl, ah, al;
        bh.u = bs4[((nt*2 + ks)*2 + 0)*64 + lane];
        bl.u = bs4[((nt*2 + ks)*2 + 1)*64 + lane];
        ah.u = Ah[ks]; al.u = Al[ks];
        acc[nt] = __builtin_amdgcn_mfma_f32_16x16x32_bf16(ah.v, bh.v, acc[nt], 0, 0, 0);
        acc[nt] = __builtin_amdgcn_mfma_f32_16x16x32_bf16(al.v, bh.v, acc[nt], 0, 0, 0);
        acc[nt] = __builtin_amdgcn_mfma_f32_16x16x32_bf16(ah.v, bl.v, acc[nt], 0, 0, 0);
      }
    }
    // D layout: col = lane&15, row = (lane>>4)*4 + reg
    if (nc < 7) {
#pragma unroll
      for (int nt = 0; nt < 4; nt++) {
#pragma unroll
        for (int reg = 0; reg < 4; reg++) {
          int node = nb0 + w * 16 + kq * 4 + reg;
          if (node < Nn)
            Y[(size_t)node * 448 + nc * 64 + nt * 16 + cl] = f2b(acc[nt][reg]);
        }
      }
    } else {
#pragma unroll
      for (int nt = 0; nt < 4; nt++) {
        int c = nt * 16 + cl;
        float bias = brel[c] + bself[c];
#pragma unroll
        for (int reg = 0; reg < 4; reg++) {
          int node = nb0 + w * 16 + kq * 4 + reg;
          if (node < Nn)
            S[(size_t)node * 64 + c] = f2b(acc[nt][reg] + bias);
        }
      }
    }
  }
}

// ---- per-node z + bias precompute ----
__global__ __launch_bounds__(256) void k_z(
    const float* __restrict__ h, const float* __restrict__ Wl1, const float* __restrict__ bl1,
    const float* __restrict__ bk2, const float* __restrict__ bn,
    u16* __restrict__ zt, u16* __restrict__ biast) {
  __shared__ float ls[64][65];
  __shared__ float zz[64][17];
  int tid = threadIdx.x;
  int nb0 = blockIdx.x * 64;
  const float* Ain = bn + 0;
  const float* Bin = bn + 64;
#pragma unroll
  for (int r = 0; r < 16; r++) {
    int idx = r * 256 + tid;
    int row = idx >> 6, col = idx & 63;
    int node = nb0 + row;
    float v = (node < Nn) ? h[(size_t)node * 64 + col] : 0.0f;
    ls[row][col] = fmaxf(v * Ain[col] + Bin[col], 0.0f);
  }
  __syncthreads();
  int row = tid >> 2, jq = (tid & 3) * 4;
  int node = nb0 + row;
  const float* Amsg = bn + 128;
  const float* Bmsg = bn + 144;
  float m1[4];
#pragma unroll
  for (int t = 0; t < 4; t++) m1[t] = bl1[jq + t];
  for (int c = 0; c < 64; c++) {
    float lv = ls[row][c];
#pragma unroll
    for (int t = 0; t < 4; t++) m1[t] += lv * Wl1[c * 16 + jq + t];
  }
  float zv[4];
#pragma unroll
  for (int t = 0; t < 4; t++) {
    zv[t] = fmaxf(m1[t] * Amsg[jq + t] + Bmsg[jq + t], 0.0f);
    zz[row][jq + t] = zv[t];
  }
  if (node < Nn) {
    u32* zg = (u32*)zt + (size_t)node * 8 + (tid & 3) * 2;
    zg[0] = pk2(zv[0], zv[1]);
    zg[1] = pk2(zv[2], zv[3]);
  }
  __syncthreads();
  float bb[4];
#pragma unroll
  for (int t = 0; t < 4; t++) bb[t] = bk2[jq + t];
  for (int j = 0; j < 16; j++) {
    float zj = zz[row][j];
#pragma unroll
    for (int t = 0; t < 4; t++) bb[t] += zj * bk2[(j + 1) * 16 + jq + t];
  }
  if (node < Nn) {
    u32* bg = (u32*)biast + (size_t)node * 8 + (tid & 3) * 2;
    bg[0] = pk2(bb[0], bb[1]);
    bg[1] = pk2(bb[2], bb[3]);
  }
}

// ---- per-edge MFMA kernel: B frags direct from L2 (no LDS staging) ----
__global__ __launch_bounds__(256) void k_msg(
    const float* __restrict__ t0, const float* __restrict__ t1, const float* __restrict__ t2,
    const float* __restrict__ r0, const float* __restrict__ r1, const float* __restrict__ r2,
    const int* __restrict__ EI, const int* __restrict__ inv,
    const u16* __restrict__ zt, const u16* __restrict__ biast,
    const u16* __restrict__ Wk1f, const float* __restrict__ bk1,
    const u16* __restrict__ BswG, u16* __restrict__ mo) {
  __shared__ u16 abuf[256 * 40];   // ef->a rows, stride 40 u16 (80 B) -> 20480 B
  __shared__ int ivin[256];        // 1024 B  (total 21504 B -> 7 blocks/CU)

  int tid = threadIdx.x;
  int e0 = blockIdx.x * 256;
  int e = e0 + tid;

  int vin = EI[e], vout = EI[Ne + e];
  ivin[tid] = vin;

  float ef[14];
  ef[0] = t0[e]; ef[1] = t1[e]; ef[2] = t2[e];
  ef[3] = r0[e]; ef[4] = r1[e]; ef[5] = r2[e];
  int ad = vin - vout; if (ad < 0) ad = -ad;
  ef[6] = ((float)ad) / 6.0f;
#pragma unroll
  for (int k = 0; k < 7; k++) ef[7+k] = 1.0f - 2.0f*fabsf(ef[k]);

  // pack ef hi/lo A-row: k=0..13 hi, 14..27 lo, 28..31 zero
  u16 row[32];
#pragma unroll
  for (int d = 0; d < 14; d++) {
    u16 hi = f2b(ef[d]);
    row[d] = hi;
    row[14 + d] = f2b(ef[d] - b2f(hi));
  }
#pragma unroll
  for (int d = 28; d < 32; d++) row[d] = 0;
  u32* ar = (u32*)(abuf + (size_t)tid * 40);
#pragma unroll
  for (int i = 0; i < 16; i++)
    ar[i] = (u32)row[2*i] | ((u32)row[2*i+1] << 16);
  __syncthreads();

  int lane = tid & 63, w4 = (tid >> 6) * 4;
  int m = lane & 15, quad = lane >> 4;
  union U { uint4 u; short8 v; };

  // a-GEMM B fragments (global, tiny L2-hot table) + bk1 per output col
  U b0[2], b1[2];
#pragma unroll
  for (int nt = 0; nt < 2; nt++) {
    b0[nt].u = *(const uint4*)(Wk1f + 0*1024 + nt*512 + lane*8);
    b1[nt].u = *(const uint4*)(Wk1f + 1*1024 + nt*512 + lane*8);
  }
  float bk1v[2] = { bk1[m], bk1[16 + m] };
  const u16* bswL = BswG + (size_t)lane * 8;   // per-lane base into B-frag table

#pragma unroll
  for (int t = 0; t < 4; t++) {
    int s0 = (w4 + t) * 16;
    const u16* rs0 = abuf + (size_t)(s0 + m) * 40;

    // ---- a = relu(ef @ Wk1 + bk1) via 2x2 MFMAs, written back in place ----
    U efr; efr.u = *(const uint4*)(rs0 + quad * 8);
#pragma unroll
    for (int nt = 0; nt < 2; nt++) {
      floatx4 aa = {0.f, 0.f, 0.f, 0.f};
      aa = __builtin_amdgcn_mfma_f32_16x16x32_bf16(efr.v, b0[nt].v, aa, 0, 0, 0);
      aa = __builtin_amdgcn_mfma_f32_16x16x32_bf16(efr.v, b1[nt].v, aa, 0, 0, 0);
#pragma unroll
      for (int reg = 0; reg < 4; reg++) {
        int se = s0 + quad * 4 + reg;
        float av = fmaxf(aa[reg] + bk1v[nt], 0.0f);
        abuf[(size_t)se * 40 + nt * 16 + m] = f2b(av);
      }
    }
    U afr; afr.u = *(const uint4*)(rs0 + quad * 8);   // re-read: now 'a'

    // ---- row metadata: z (2x uint4), bias, out slot for the 4 owned rows ----
    int se0 = s0 + quad * 4;
    uint4 z0[4], z1[4]; float bv[4]; int sl[4];
#pragma unroll
    for (int reg = 0; reg < 4; reg++) {
      int vi = ivin[se0 + reg];
      const uint4* zp = (const uint4*)(zt + (size_t)vi * 16);
      z0[reg] = zp[0]; z1[reg] = zp[1];
      bv[reg] = b2f(biast[(size_t)vi * 16 + m]);
      sl[reg] = inv[e0 + se0 + reg];
    }

    // ---- ker MFMAs (B frags from L2) with immediate per-jp consume ----
    float acc[4];
    {
      U bfr; bfr.u = *(const uint4*)(bswL);
      floatx4 zz4 = {0.f, 0.f, 0.f, 0.f};
      floatx4 k0 = __builtin_amdgcn_mfma_f32_16x16x32_bf16(afr.v, bfr.v, zz4, 0, 0, 0);
#pragma unroll
      for (int reg = 0; reg < 4; reg++) acc[reg] = k0[reg];
    }
#pragma unroll
    for (int jp = 1; jp <= 16; jp++) {
      U bfr; bfr.u = *(const uint4*)(bswL + (size_t)jp * 512);
      floatx4 zz4 = {0.f, 0.f, 0.f, 0.f};
      floatx4 kj = __builtin_amdgcn_mfma_f32_16x16x32_bf16(afr.v, bfr.v, zz4, 0, 0, 0);
      const int zi = jp - 1;
#pragma unroll
      for (int reg = 0; reg < 4; reg++) {
        const u32* zw = (zi < 8) ? (const u32*)&z0[reg] : (const u32*)&z1[reg];
        u32 wv = zw[(zi & 7) >> 1];
        float zv = (zi & 1) ? hi2f(wv) : lo2f(wv);
        acc[reg] += zv * kj[reg];
      }
    }
#pragma unroll
    for (int reg = 0; reg < 4; reg++)
      mo[(size_t)sl[reg] * 16 + m] = f2b(acc[reg] + bv[reg]);
  }
}

// ---- per-node: prefetch-everything + 2x-unrolled Y gather + mo sum, residual, LN ----
__global__ __launch_bounds__(256) void k_node(
    const float* __restrict__ h, const u16* __restrict__ S, const u16* __restrict__ Y,
    const int* __restrict__ rowptr, const int* __restrict__ yidx,
    const u16* __restrict__ mo, const float* __restrict__ deginv,
    const float* __restrict__ Wl2, const float* __restrict__ bl2,
    const float* __restrict__ bn, const float* __restrict__ lng, const float* __restrict__ lnb,
    float* __restrict__ hout) {
  __shared__ float relsm[4][64];
  __shared__ float u2s[4][16];
  int tid = threadIdx.x;
  int lane = tid & 63, w = tid >> 6;
  int n = blockIdx.x * 4 + w;
  bool act = (n < Nn);

  float hval = 0.0f, sval = 0.0f, di = 1.0f;
  if (act) {
    int beg = rowptr[n], end = rowptr[n+1];

    // ---- early issue: tail loads + part-B round-0 load (hide under part A) ----
    hval = h[(size_t)n*64 + lane];
    sval = b2f(S[(size_t)n*64 + lane]);
    di = deginv[n];
    int r = lane >> 2, c4 = lane & 3;
    int pf = beg + r;
    uint2 dB0 = make_uint2(0u, 0u);
    if (pf < end) dB0 = *(const uint2*)(mo + (size_t)pf * 16 + c4 * 4);

    // ---- part A: rel sum over Y rows; 2 rounds unrolled -> 2 loads in flight ----
    int g = lane >> 4, col4 = lane & 15;
    float a4[4] = {0.f, 0.f, 0.f, 0.f};
    for (int c0 = beg; c0 < end; c0 += 64) {
      int l = c0 + lane;
      int yo = (l < end) ? yidx[l] : 0;
      int cnt = end - c0; if (cnt > 64) cnt = 64;
      for (int j0 = 0; j0 < cnt; j0 += 8) {
        int jA = j0 + g;
        int jB = j0 + 4 + g;
        int yA = __shfl(yo, jA, 64);
        int yB = __shfl(yo, jB, 64);
        bool vA = (jA < cnt), vB = (jB < cnt);
        uint2 dA = vA ? *(const uint2*)(Y + (size_t)yA + col4 * 4) : make_uint2(0u, 0u);
        uint2 dB = vB ? *(const uint2*)(Y + (size_t)yB + col4 * 4) : make_uint2(0u, 0u);
        a4[0] += lo2f(dA.x); a4[1] += hi2f(dA.x);
        a4[2] += lo2f(dA.y); a4[3] += hi2f(dA.y);
        a4[0] += lo2f(dB.x); a4[1] += hi2f(dB.x);
        a4[2] += lo2f(dB.y); a4[3] += hi2f(dB.y);
      }
    }
#pragma unroll
    for (int t = 0; t < 4; t++) {
      a4[t] += __shfl_xor(a4[t], 16, 64);
      a4[t] += __shfl_xor(a4[t], 32, 64);
    }
    if (lane < 16) {
#pragma unroll
      for (int t = 0; t < 4; t++) relsm[w][col4 * 4 + t] = a4[t];
    }

    // ---- part B: mo sum; round 0 already in dB0, rest streamed ----
    float p4[4] = { lo2f(dB0.x), hi2f(dB0.x), lo2f(dB0.y), hi2f(dB0.y) };
    for (int p0 = beg + 16; p0 < end; p0 += 16) {
      int p = p0 + r;
      if (p < end) {
        uint2 d = *(const uint2*)(mo + (size_t)p * 16 + c4 * 4);
        p4[0] += lo2f(d.x); p4[1] += hi2f(d.x);
        p4[2] += lo2f(d.y); p4[3] += hi2f(d.y);
      }
    }
#pragma unroll
    for (int t = 0; t < 4; t++) {
      p4[t] += __shfl_xor(p4[t],  4, 64);
      p4[t] += __shfl_xor(p4[t],  8, 64);
      p4[t] += __shfl_xor(p4[t], 16, 64);
      p4[t] += __shfl_xor(p4[t], 32, 64);
    }
    const float* Aupd = bn + 160;
    const float* Bupd = bn + 176;
    if (lane < 4) {
#pragma unroll
      for (int t = 0; t < 4; t++) {
        int col = c4 * 4 + t;
        float v = p4[t] * di;
        u2s[w][col] = fmaxf(v * Aupd[col] + Bupd[col], 0.0f);
      }
    }
  }
  __syncthreads();
  if (act) {
    float rel_out = fmaxf(sval + relsm[w][lane], 0.0f);
    float ie = bl2[lane];
#pragma unroll
    for (int j = 0; j < 16; j++) ie += u2s[w][j] * Wl2[j*64 + lane];
    const float* Aout = bn + 192;
    const float* Bout = bn + 256;
    ie = ie * Aout[lane] + Bout[lane];
    float hidden = rel_out + ie + hval;
    float s = hidden;
#pragma unroll
    for (int off = 32; off > 0; off >>= 1) s += __shfl_xor(s, off, 64);
    float mu = s * (1.0f/64.0f);
    float d = hidden - mu;
    float s2 = d * d;
#pragma unroll
    for (int off = 32; off > 0; off >>= 1) s2 += __shfl_xor(s2, off, 64);
    float var = s2 * (1.0f/64.0f);
    float o = d * rsqrtf(var + 1e-5f) * lng[lane] + lnb[lane];
    hout[(size_t)n*64 + lane] = o;
  }
}

extern "C" void kernel_launch(void* const* d_in, const int* in_sizes, int n_in,
                              void* d_out, int out_size, void* d_ws, size_t ws_size,
                              hipStream_t stream) {
  const float* x    = (const float*)d_in[0];
  const float* posf = (const float*)d_in[1];
  const int* EI     = (const int*)d_in[2];
  const int* EREL   = (const int*)d_in[3];
  float* outf       = (float*)d_out;

  char* p = (char*)d_ws;
  auto alloc = [&](size_t bytes) -> char* {
    char* r = p;
    p += (bytes + 255) & ~((size_t)255);
    return r;
  };
  float* W      = (float*)alloc((size_t)135744 * 4);
  float* bnAB   = (float*)alloc((size_t)960 * 4);
  u16*   BswG   = (u16*)  alloc((size_t)3 * 8704 * 2);
  u16*   Bsw2   = (u16*)  alloc((size_t)3 * 65536 * 2);
  u16*   Wk1f   = (u16*)  alloc((size_t)3 * 2048 * 2);
  float* u      = (float*)alloc((size_t)Nn * 3 * 4);
  float* frame  = (float*)alloc((size_t)Nn * 9 * 4);
  int*   cnt    = (int*)  alloc((size_t)Nn * 4);
  int*   fill   = (int*)  alloc((size_t)Nn * 4);
  int*   rowptr = (int*)  alloc((size_t)(Nn + 1) * 4);
  int*   locExc = (int*)  alloc((size_t)Nn * 4);
  int*   btot   = (int*)  alloc((size_t)SCAN_B * 4);
  int*   boff   = (int*)  alloc((size_t)SCAN_B * 4);
  int*   yidx   = (int*)  alloc((size_t)Ne * 4);
  int*   inv    = (int*)  alloc((size_t)Ne * 4);
  float* deginv = (float*)alloc((size_t)Nn * 4);
  float* h      = (float*)alloc((size_t)Nn * 64 * 4);
  u16*   S      = (u16*)  alloc((size_t)Nn * 64 * 2);
  u16*   Y      = (u16*)  alloc((size_t)Nn * 448 * 2);
  u16*   mo     = (u16*)  alloc((size_t)Ne * 16 * 2);
  u16*   zt     = (u16*)  alloc((size_t)Nn * 16 * 2);
  u16*   biast  = (u16*)  alloc((size_t)Nn * 16 * 2);
  float* et0    = (float*)alloc((size_t)Ne * 4);
  float* et1    = (float*)alloc((size_t)Ne * 4);
  float* et2    = (float*)alloc((size_t)Ne * 4);
  float* er0    = (float*)alloc((size_t)Ne * 4);
  float* er1    = (float*)alloc((size_t)Ne * 4);
  float* er2    = (float*)alloc((size_t)Ne * 4);
  (void)n_in; (void)in_sizes; (void)out_size;

  size_t needed = (size_t)(p - (char*)d_ws);
  if (needed > ws_size) return;  // diagnostic: zero output => absmax == max|ref| (~4.75)

  hipMemsetAsync(cnt,  0, (size_t)Nn * 4, stream);
  hipMemsetAsync(fill, 0, (size_t)Nn * 4, stream);

  for (int k = 0; k < 18; k++)
    hipMemcpyAsync(W + H_CUM[k], d_in[4 + k], (size_t)H_SZ[k] * 4,
                   hipMemcpyDeviceToDevice, stream);
  hipMemcpyAsync(h, x, (size_t)Nn * 64 * 4, hipMemcpyDeviceToDevice, stream);

  k_bnprep<<<2, 256, 0, stream>>>(W, bnAB);
  k_prep<<<(3*8704 + 255)/256, 256, 0, stream>>>(W, BswG);
  k_prep2<<<(3*65536 + 255)/256, 256, 0, stream>>>(W, Bsw2);
  k_prep3<<<(3*2048 + 255)/256, 256, 0, stream>>>(W, Wk1f);
  k_u<<<(Nn + 255)/256, 256, 0, stream>>>(posf, u);
  k_frame<<<(Nn + 255)/256, 256, 0, stream>>>(u, frame);
  k_edge<<<Ne/256, 256, 0, stream>>>(EI, posf, frame, et0, et1, et2, er0, er1, er2, cnt);
  k_scan1<<<SCAN_B, 1024, 0, stream>>>(cnt, locExc, btot);
  k_scan2<<<1, 64, 0, stream>>>(btot, boff, rowptr);
  k_scan3<<<(Nn + 255)/256, 256, 0, stream>>>(cnt, locExc, boff, rowptr, deginv);
  k_place<<<Ne/256, 256, 0, stream>>>(EI, EREL, rowptr, fill, yidx, inv);

  for (int i = 0; i < Ll; i++) {
    const float* brel  = W + H_CUM[1]  + i * 64;
    const float* bself = W + H_CUM[3]  + i * 64;
    const float* Wl1   = W + H_CUM[4]  + i * 1024;
    const float* bl1   = W + H_CUM[5]  + i * 16;
    const float* bk1   = W + H_CUM[7]  + i * 32;
    const float* bk2   = W + H_CUM[9]  + i * 272;
    const float* Wl2   = W + H_CUM[10] + i * 1024;
    const float* bl2   = W + H_CUM[11] + i * 64;
    const float* lng   = W + H_CUM[16] + i * 64;
    const float* lnb   = W + H_CUM[17] + i * 64;
    const float* bnL   = bnAB + i * 320;
    const u16*   BswL  = BswG + i * 8704;

    k_rel2<<<(Nn + 63)/64, 256, 0, stream>>>(h, Bsw2 + i * 65536, brel, bself, Y, S);
    k_z<<<(Nn + 63)/64, 256, 0, stream>>>(h, Wl1, bl1, bk2, bnL, zt, biast);
    k_msg<<<Ne/256, 256, 0, stream>>>(et0, et1, et2, er0, er1, er2, EI, inv,
                                      zt, biast, Wk1f + i * 2048, bk1, BswL, mo);
    k_node<<<(Nn + 3)/4, 256, 0, stream>>>(h, S, Y, rowptr, yidx, mo, deginv,
                                           Wl2, bl2, bnL, lng, lnb,
                                           (i == Ll - 1) ? outf : h);
  }
}